// Round 1
// baseline (2602.843 us; speedup 1.0000x reference)
//
#include <hip/hip_runtime.h>
#include <hip/hip_bf16.h>
#include <cstdint>

// ---------------------------------------------------------------------------
// MoE CNN, hard top-1 dispatch. fp32 baseline (correctness-first).
// Sizes: B=1024, Cin=3, HW=32, GC=16, E=4, C1=64, C2=128, FC_IN=8192, NC=100
// Output: [final 1024*100][probs 1024*4][aux 1]
// ---------------------------------------------------------------------------

#define B_TOT 1024

// ---------------- K1: gate conv(3->16,3x3 SAME)+relu+gap -> g_mean[B,16] ----
__global__ __launch_bounds__(256) void k_gate(
    const float* __restrict__ x, const float* __restrict__ gcw,
    const float* __restrict__ gcb, float* __restrict__ g_mean) {
  const int b = blockIdx.x;
  const int tid = threadIdx.x;
  const int wave = tid >> 6, lane = tid & 63;
  const float* xb = x + (size_t)b * 3072;

  float sums[16];
#pragma unroll
  for (int c = 0; c < 16; c++) sums[c] = 0.f;

  for (int k = 0; k < 4; k++) {
    const int p = tid + 256 * k;
    const int y = p >> 5, xx = p & 31;
    float acc[16];
#pragma unroll
    for (int c = 0; c < 16; c++) acc[c] = 0.f;
#pragma unroll
    for (int ci = 0; ci < 3; ci++) {
      float pv[9];
#pragma unroll
      for (int ky = 0; ky < 3; ky++)
#pragma unroll
        for (int kx = 0; kx < 3; kx++) {
          const int iy = y + ky - 1, ix = xx + kx - 1;
          const bool ok = (iy >= 0) && (iy < 32) && (ix >= 0) && (ix < 32);
          const int iyc = min(max(iy, 0), 31), ixc = min(max(ix, 0), 31);
          const float v = xb[ci * 1024 + iyc * 32 + ixc];
          pv[ky * 3 + kx] = ok ? v : 0.f;
        }
#pragma unroll
      for (int c = 0; c < 16; c++)
#pragma unroll
        for (int t = 0; t < 9; t++)
          acc[c] += pv[t] * gcw[(c * 3 + ci) * 9 + t];
    }
#pragma unroll
    for (int c = 0; c < 16; c++) sums[c] += fmaxf(acc[c] + gcb[c], 0.f);
  }

  __shared__ float red[4 * 16];
#pragma unroll
  for (int c = 0; c < 16; c++) {
    float v = sums[c];
    for (int o = 32; o > 0; o >>= 1) v += __shfl_down(v, o);
    if (lane == 0) red[wave * 16 + c] = v;
  }
  __syncthreads();
  if (tid < 16) {
    const float tot = red[tid] + red[16 + tid] + red[32 + tid] + red[48 + tid];
    g_mean[b * 16 + tid] = tot * (1.f / 1024.f);
  }
}

// ---------------- K2: router linear+softmax, argmax, counts ----------------
__global__ __launch_bounds__(256) void k_router(
    const float* __restrict__ g_mean, const float* __restrict__ gfw,
    const float* __restrict__ gfb, float* __restrict__ probs,
    float* __restrict__ best_w, int* __restrict__ best_idx,
    int* __restrict__ counts) {
  const int b = blockIdx.x * 256 + threadIdx.x;
  float g[16];
#pragma unroll
  for (int c = 0; c < 16; c++) g[c] = g_mean[b * 16 + c];
  float lg[4];
#pragma unroll
  for (int e = 0; e < 4; e++) {
    float s = gfb[e];
#pragma unroll
    for (int c = 0; c < 16; c++) s += g[c] * gfw[e * 16 + c];
    lg[e] = s;
  }
  float m = fmaxf(fmaxf(lg[0], lg[1]), fmaxf(lg[2], lg[3]));
  float ex[4], s = 0.f;
#pragma unroll
  for (int e = 0; e < 4; e++) { ex[e] = expf(lg[e] - m); s += ex[e]; }
  const float inv = 1.f / s;
  float p[4];
#pragma unroll
  for (int e = 0; e < 4; e++) { p[e] = ex[e] * inv; probs[b * 4 + e] = p[e]; }
  int bi = 0; float bp = p[0];
#pragma unroll
  for (int e = 1; e < 4; e++) if (p[e] > bp) { bp = p[e]; bi = e; }
  best_w[b] = bp;
  best_idx[b] = bi;
  atomicAdd(&counts[bi], 1);
}

// ---------------- K2c: 32-aligned segment offsets --------------------------
__global__ void k_offsets(const int* __restrict__ counts, int* __restrict__ off) {
  if (threadIdx.x == 0) {
    int o = 0;
    for (int e = 0; e < 4; e++) { off[e] = o; o += ((counts[e] + 31) & ~31); }
    off[4] = o;
  }
}

// ---------------- K2d: scatter sample ids grouped by expert ----------------
__global__ __launch_bounds__(256) void k_scatter(
    const int* __restrict__ best_idx, const int* __restrict__ off,
    int* __restrict__ cnt2, int* __restrict__ order) {
  const int b = blockIdx.x * 256 + threadIdx.x;
  const int e = best_idx[b];
  const int slot = off[e] + atomicAdd(&cnt2[e], 1);
  order[slot] = b;
}

// ---------------- K3: aux loss ---------------------------------------------
__global__ __launch_bounds__(256) void k_aux(const float* __restrict__ probs,
                                             float* __restrict__ aux_out) {
  __shared__ float red[16];
  const int t = threadIdx.x;
  const int wave = t >> 6, lane = t & 63;
  float sums[4] = {0.f, 0.f, 0.f, 0.f};
  for (int b = t; b < B_TOT; b += 256) {
#pragma unroll
    for (int e = 0; e < 4; e++) sums[e] += probs[b * 4 + e];
  }
#pragma unroll
  for (int e = 0; e < 4; e++) {
    float v = sums[e];
    for (int o = 32; o > 0; o >>= 1) v += __shfl_down(v, o);
    if (lane == 0) red[wave * 4 + e] = v;
  }
  __syncthreads();
  if (t == 0) {
    float aux = 0.f;
#pragma unroll
    for (int e = 0; e < 4; e++) {
      const float mp = (red[e] + red[4 + e] + red[8 + e] + red[12 + e]) * (1.f / 1024.f);
      const float d = mp - 0.25f;
      aux += d * d;
    }
    aux_out[0] = aux * 0.25f;
  }
}

// ---------------- K4: expert conv1(3->64)+relu+pool -> h1[B,64,16,16] ------
// wave-per-64-pooled-pixels, 8-channel groups, weights via uniform (scalar) loads
__global__ __launch_bounds__(256, 2) void k_conv1(
    const float* __restrict__ x, const float* __restrict__ w1,
    const float* __restrict__ b1, const int* __restrict__ best_idx,
    float* __restrict__ h1ws) {
  const int b = blockIdx.x;
  const int tid = threadIdx.x;
  const int wave = __builtin_amdgcn_readfirstlane(tid >> 6);
  const int lane = tid & 63;
  const int e = __builtin_amdgcn_readfirstlane(best_idx[b]);
  const int pos = wave * 64 + lane;  // pooled position 0..255
  const int py = pos >> 4, px = pos & 15;
  const float* xb = x + (size_t)b * 3072;
  const float* w1e = w1 + (size_t)e * 1728;
  const float* b1e = b1 + (size_t)e * 64;
  float* h1b = h1ws + (size_t)b * 16384;

  int ry[4], cx[4];
  float my[4], mx_[4];
#pragma unroll
  for (int i = 0; i < 4; i++) {
    const int yy = 2 * py - 1 + i;
    my[i] = (yy >= 0 && yy < 32) ? 1.f : 0.f;
    ry[i] = min(max(yy, 0), 31) * 32;
    const int xx = 2 * px - 1 + i;
    mx_[i] = (xx >= 0 && xx < 32) ? 1.f : 0.f;
    cx[i] = min(max(xx, 0), 31);
  }
  float mm[16];
#pragma unroll
  for (int i = 0; i < 4; i++)
#pragma unroll
    for (int j = 0; j < 4; j++) mm[i * 4 + j] = my[i] * mx_[j];

  for (int g = 0; g < 8; g++) {
    const int co0 = g * 8;
    float acc[8][4];
#pragma unroll
    for (int m = 0; m < 8; m++)
#pragma unroll
      for (int q = 0; q < 4; q++) acc[m][q] = 0.f;
#pragma unroll
    for (int ci = 0; ci < 3; ci++) {
      float pv[16];
#pragma unroll
      for (int i = 0; i < 4; i++)
#pragma unroll
        for (int j = 0; j < 4; j++)
          pv[i * 4 + j] = xb[ci * 1024 + ry[i] + cx[j]] * mm[i * 4 + j];
#pragma unroll
      for (int m = 0; m < 8; m++) {
        const float* wr = w1e + (co0 + m) * 27 + ci * 9;
#pragma unroll
        for (int ky = 0; ky < 3; ky++)
#pragma unroll
          for (int kx = 0; kx < 3; kx++) {
            const float wv = wr[ky * 3 + kx];
#pragma unroll
            for (int dy = 0; dy < 2; dy++)
#pragma unroll
              for (int dx = 0; dx < 2; dx++)
                acc[m][dy * 2 + dx] += wv * pv[(ky + dy) * 4 + (kx + dx)];
          }
      }
    }
#pragma unroll
    for (int m = 0; m < 8; m++) {
      float v = fmaxf(fmaxf(acc[m][0], acc[m][1]), fmaxf(acc[m][2], acc[m][3]));
      v = fmaxf(v + b1e[co0 + m], 0.f);
      h1b[(co0 + m) * 256 + pos] = v;
    }
  }
}

// ---------------- K4b: expert conv2(64->128)+relu+pool -> h2[B,8192] -------
// ci-outer, all 32 c_out accumulators live per wave: 16 patch loads / 1152 FMA
__global__ __launch_bounds__(256, 2) void k_conv2(
    const float* __restrict__ h1ws, const float* __restrict__ w2,
    const float* __restrict__ b2, const int* __restrict__ best_idx,
    float* __restrict__ h2ws) {
  const int b = blockIdx.x;
  const int tid = threadIdx.x;
  const int wave = __builtin_amdgcn_readfirstlane(tid >> 6);
  const int lane = tid & 63;
  const int e = __builtin_amdgcn_readfirstlane(best_idx[b]);
  const int py = lane >> 3, px = lane & 7;  // pooled pos in 8x8
  const int co0 = wave * 32;
  const float* h1b = h1ws + (size_t)b * 16384;
  const float* w2e = w2 + (size_t)e * 73728;

  int ry[4], cx[4];
  float my[4], mx_[4];
#pragma unroll
  for (int i = 0; i < 4; i++) {
    const int yy = 2 * py - 1 + i;
    my[i] = (yy >= 0 && yy < 16) ? 1.f : 0.f;
    ry[i] = min(max(yy, 0), 15) * 16;
    const int xx = 2 * px - 1 + i;
    mx_[i] = (xx >= 0 && xx < 16) ? 1.f : 0.f;
    cx[i] = min(max(xx, 0), 15);
  }
  float mm[16];
#pragma unroll
  for (int i = 0; i < 4; i++)
#pragma unroll
    for (int j = 0; j < 4; j++) mm[i * 4 + j] = my[i] * mx_[j];

  float acc[32][4];
#pragma unroll
  for (int m = 0; m < 32; m++)
#pragma unroll
    for (int q = 0; q < 4; q++) acc[m][q] = 0.f;

  for (int ci = 0; ci < 64; ci++) {
    float pv[16];
#pragma unroll
    for (int i = 0; i < 4; i++)
#pragma unroll
      for (int j = 0; j < 4; j++)
        pv[i * 4 + j] = h1b[ci * 256 + ry[i] + cx[j]] * mm[i * 4 + j];
#pragma unroll
    for (int m = 0; m < 32; m++) {
      const float* wr = w2e + (co0 + m) * 576 + ci * 9;
#pragma unroll
      for (int ky = 0; ky < 3; ky++)
#pragma unroll
        for (int kx = 0; kx < 3; kx++) {
          const float wv = wr[ky * 3 + kx];
#pragma unroll
          for (int dy = 0; dy < 2; dy++)
#pragma unroll
            for (int dx = 0; dx < 2; dx++)
              acc[m][dy * 2 + dx] += wv * pv[(ky + dy) * 4 + (kx + dx)];
        }
    }
  }

#pragma unroll
  for (int m = 0; m < 32; m++) {
    float v = fmaxf(fmaxf(acc[m][0], acc[m][1]), fmaxf(acc[m][2], acc[m][3]));
    v = fmaxf(v + b2[e * 128 + co0 + m], 0.f);
    h2ws[(size_t)b * 8192 + (co0 + m) * 64 + lane] = v;
  }
}

// ---------------- K5: FC, expert-grouped, split-K, atomic combine ----------
__global__ __launch_bounds__(256) void k_fc(
    const float* __restrict__ h2ws, const float* __restrict__ efw,
    const float* __restrict__ efb, const int* __restrict__ order,
    const int* __restrict__ off, const int* __restrict__ counts,
    const float* __restrict__ best_w, float* __restrict__ out) {
  const int tix = blockIdx.x;  // 0..35 sample tiles of 32
  const int ks = blockIdx.y;   // 0..7 k-slices of 1024
  const int base = tix * 32;
  if (base >= off[4]) return;
  int e = 0;
#pragma unroll
  for (int i = 1; i < 4; i++) if (base >= off[i]) e = i;
  const int vend = off[e] + counts[e];
  const int t = threadIdx.x;
  const int r = t >> 3, og = t & 7;
  const int pos = base + r;
  if (pos >= vend) return;
  const int s = order[pos];
  const float* a = h2ws + (size_t)s * 8192 + ks * 1024;
  const float* wbase = efw + (size_t)e * 819200 + ks * 1024;
  const float* wp[13];
#pragma unroll
  for (int j = 0; j < 13; j++) {
    int o = og + 8 * j;
    if (o > 99) o = 99;
    wp[j] = wbase + (size_t)o * 8192;
  }
  float acc[13];
#pragma unroll
  for (int j = 0; j < 13; j++) acc[j] = 0.f;
  for (int k = 0; k < 1024; k++) {
    const float av = a[k];
#pragma unroll
    for (int j = 0; j < 13; j++) acc[j] += av * wp[j][k];
  }
  const float bw = best_w[s];
#pragma unroll
  for (int j = 0; j < 13; j++) {
    const int o = og + 8 * j;
    if (o < 100) {
      float v = acc[j] * bw;
      if (ks == 0) v += efb[e * 100 + o] * bw;
      atomicAdd(out + (size_t)s * 100 + o, v);
    }
  }
}

// ---------------------------------------------------------------------------
extern "C" void kernel_launch(void* const* d_in, const int* in_sizes, int n_in,
                              void* d_out, int out_size, void* d_ws, size_t ws_size,
                              hipStream_t stream) {
  const float* x   = (const float*)d_in[0];
  const float* gcw = (const float*)d_in[1];
  const float* gcb = (const float*)d_in[2];
  const float* gfw = (const float*)d_in[3];
  const float* gfb = (const float*)d_in[4];
  const float* c1w = (const float*)d_in[5];
  const float* c1b = (const float*)d_in[6];
  const float* c2w = (const float*)d_in[7];
  const float* c2b = (const float*)d_in[8];
  const float* efw = (const float*)d_in[9];
  const float* efb = (const float*)d_in[10];
  float* out = (float*)d_out;
  float* ws  = (float*)d_ws;

  // ws layout (float elements)
  float* g_mean  = ws;                      // 16384
  float* best_w  = ws + 16384;              // 1024
  int*   best_idx = (int*)(ws + 17408);     // 1024
  int*   counts   = (int*)(ws + 18432);     // 4
  int*   cnt2     = (int*)(ws + 18436);     // 4
  int*   off      = (int*)(ws + 18440);     // 5
  int*   order    = (int*)(ws + 18448);     // 1152
  float* h1 = ws + 20480;                   // 1024*64*16*16 = 16777216
  float* h2 = ws + 16797696;                // 1024*8192     = 8388608

  float* probs = out + 102400;
  float* aux   = out + 106496;

  hipMemsetAsync(out, 0, 102400 * sizeof(float), stream);      // atomic target
  hipMemsetAsync(counts, 0, 8 * sizeof(int), stream);          // counts + cnt2

  k_gate<<<1024, 256, 0, stream>>>(x, gcw, gcb, g_mean);
  k_router<<<4, 256, 0, stream>>>(g_mean, gfw, gfb, probs, best_w, best_idx, counts);
  k_offsets<<<1, 64, 0, stream>>>(counts, off);
  k_scatter<<<4, 256, 0, stream>>>(best_idx, off, cnt2, order);
  k_aux<<<1, 256, 0, stream>>>(probs, aux);
  k_conv1<<<1024, 256, 0, stream>>>(x, c1w, c1b, best_idx, h1);
  k_conv2<<<1024, 256, 0, stream>>>(h1, c2w, c2b, best_idx, h2);
  dim3 g5(36, 8);
  k_fc<<<g5, 256, 0, stream>>>(h2, efw, efb, order, off, counts, best_w, out);
}

// Round 2
// 1387.292 us; speedup vs baseline: 1.8762x; 1.8762x over previous
//
#include <hip/hip_runtime.h>
#include <hip/hip_bf16.h>
#include <cstdint>

// ---------------------------------------------------------------------------
// MoE CNN, hard top-1 dispatch. fp32 baseline, round 2: fixed k_fc.
// Sizes: B=1024, Cin=3, HW=32, GC=16, E=4, C1=64, C2=128, FC_IN=8192, NC=100
// Output: [final 1024*100][probs 1024*4][aux 1]
// ---------------------------------------------------------------------------

#define B_TOT 1024
#define FC_KS 32
#define FC_CHUNK 256  // 8192 / FC_KS

// ---------------- K1: gate conv(3->16,3x3 SAME)+relu+gap -> g_mean[B,16] ----
__global__ __launch_bounds__(256) void k_gate(
    const float* __restrict__ x, const float* __restrict__ gcw,
    const float* __restrict__ gcb, float* __restrict__ g_mean) {
  const int b = blockIdx.x;
  const int tid = threadIdx.x;
  const int wave = tid >> 6, lane = tid & 63;
  const float* xb = x + (size_t)b * 3072;

  float sums[16];
#pragma unroll
  for (int c = 0; c < 16; c++) sums[c] = 0.f;

  for (int k = 0; k < 4; k++) {
    const int p = tid + 256 * k;
    const int y = p >> 5, xx = p & 31;
    float acc[16];
#pragma unroll
    for (int c = 0; c < 16; c++) acc[c] = 0.f;
#pragma unroll
    for (int ci = 0; ci < 3; ci++) {
      float pv[9];
#pragma unroll
      for (int ky = 0; ky < 3; ky++)
#pragma unroll
        for (int kx = 0; kx < 3; kx++) {
          const int iy = y + ky - 1, ix = xx + kx - 1;
          const bool ok = (iy >= 0) && (iy < 32) && (ix >= 0) && (ix < 32);
          const int iyc = min(max(iy, 0), 31), ixc = min(max(ix, 0), 31);
          const float v = xb[ci * 1024 + iyc * 32 + ixc];
          pv[ky * 3 + kx] = ok ? v : 0.f;
        }
#pragma unroll
      for (int c = 0; c < 16; c++)
#pragma unroll
        for (int t = 0; t < 9; t++)
          acc[c] += pv[t] * gcw[(c * 3 + ci) * 9 + t];
    }
#pragma unroll
    for (int c = 0; c < 16; c++) sums[c] += fmaxf(acc[c] + gcb[c], 0.f);
  }

  __shared__ float red[4 * 16];
#pragma unroll
  for (int c = 0; c < 16; c++) {
    float v = sums[c];
    for (int o = 32; o > 0; o >>= 1) v += __shfl_down(v, o);
    if (lane == 0) red[wave * 16 + c] = v;
  }
  __syncthreads();
  if (tid < 16) {
    const float tot = red[tid] + red[16 + tid] + red[32 + tid] + red[48 + tid];
    g_mean[b * 16 + tid] = tot * (1.f / 1024.f);
  }
}

// ---------------- K2: router linear+softmax, argmax, counts ----------------
__global__ __launch_bounds__(256) void k_router(
    const float* __restrict__ g_mean, const float* __restrict__ gfw,
    const float* __restrict__ gfb, float* __restrict__ probs,
    float* __restrict__ best_w, int* __restrict__ best_idx,
    int* __restrict__ counts) {
  const int b = blockIdx.x * 256 + threadIdx.x;
  float g[16];
#pragma unroll
  for (int c = 0; c < 16; c++) g[c] = g_mean[b * 16 + c];
  float lg[4];
#pragma unroll
  for (int e = 0; e < 4; e++) {
    float s = gfb[e];
#pragma unroll
    for (int c = 0; c < 16; c++) s += g[c] * gfw[e * 16 + c];
    lg[e] = s;
  }
  float m = fmaxf(fmaxf(lg[0], lg[1]), fmaxf(lg[2], lg[3]));
  float ex[4], s = 0.f;
#pragma unroll
  for (int e = 0; e < 4; e++) { ex[e] = expf(lg[e] - m); s += ex[e]; }
  const float inv = 1.f / s;
  float p[4];
#pragma unroll
  for (int e = 0; e < 4; e++) { p[e] = ex[e] * inv; probs[b * 4 + e] = p[e]; }
  int bi = 0; float bp = p[0];
#pragma unroll
  for (int e = 1; e < 4; e++) if (p[e] > bp) { bp = p[e]; bi = e; }
  best_w[b] = bp;
  best_idx[b] = bi;
  atomicAdd(&counts[bi], 1);
}

// ---------------- K2c: 32-aligned segment offsets --------------------------
__global__ void k_offsets(const int* __restrict__ counts, int* __restrict__ off) {
  if (threadIdx.x == 0) {
    int o = 0;
    for (int e = 0; e < 4; e++) { off[e] = o; o += ((counts[e] + 31) & ~31); }
    off[4] = o;
  }
}

// ---------------- K2d: scatter sample ids grouped by expert ----------------
__global__ __launch_bounds__(256) void k_scatter(
    const int* __restrict__ best_idx, const int* __restrict__ off,
    int* __restrict__ cnt2, int* __restrict__ order) {
  const int b = blockIdx.x * 256 + threadIdx.x;
  const int e = best_idx[b];
  const int slot = off[e] + atomicAdd(&cnt2[e], 1);
  order[slot] = b;
}

// ---------------- K3: aux loss ---------------------------------------------
__global__ __launch_bounds__(256) void k_aux(const float* __restrict__ probs,
                                             float* __restrict__ aux_out) {
  __shared__ float red[16];
  const int t = threadIdx.x;
  const int wave = t >> 6, lane = t & 63;
  float sums[4] = {0.f, 0.f, 0.f, 0.f};
  for (int b = t; b < B_TOT; b += 256) {
#pragma unroll
    for (int e = 0; e < 4; e++) sums[e] += probs[b * 4 + e];
  }
#pragma unroll
  for (int e = 0; e < 4; e++) {
    float v = sums[e];
    for (int o = 32; o > 0; o >>= 1) v += __shfl_down(v, o);
    if (lane == 0) red[wave * 4 + e] = v;
  }
  __syncthreads();
  if (t == 0) {
    float aux = 0.f;
#pragma unroll
    for (int e = 0; e < 4; e++) {
      const float mp = (red[e] + red[4 + e] + red[8 + e] + red[12 + e]) * (1.f / 1024.f);
      const float d = mp - 0.25f;
      aux += d * d;
    }
    aux_out[0] = aux * 0.25f;
  }
}

// ---------------- K4: expert conv1(3->64)+relu+pool -> h1[B,64,16,16] ------
__global__ __launch_bounds__(256, 2) void k_conv1(
    const float* __restrict__ x, const float* __restrict__ w1,
    const float* __restrict__ b1, const int* __restrict__ best_idx,
    float* __restrict__ h1ws) {
  const int b = blockIdx.x;
  const int tid = threadIdx.x;
  const int wave = __builtin_amdgcn_readfirstlane(tid >> 6);
  const int lane = tid & 63;
  const int e = __builtin_amdgcn_readfirstlane(best_idx[b]);
  const int pos = wave * 64 + lane;  // pooled position 0..255
  const int py = pos >> 4, px = pos & 15;
  const float* xb = x + (size_t)b * 3072;
  const float* w1e = w1 + (size_t)e * 1728;
  const float* b1e = b1 + (size_t)e * 64;
  float* h1b = h1ws + (size_t)b * 16384;

  int ry[4], cx[4];
  float my[4], mx_[4];
#pragma unroll
  for (int i = 0; i < 4; i++) {
    const int yy = 2 * py - 1 + i;
    my[i] = (yy >= 0 && yy < 32) ? 1.f : 0.f;
    ry[i] = min(max(yy, 0), 31) * 32;
    const int xx = 2 * px - 1 + i;
    mx_[i] = (xx >= 0 && xx < 32) ? 1.f : 0.f;
    cx[i] = min(max(xx, 0), 31);
  }
  float mm[16];
#pragma unroll
  for (int i = 0; i < 4; i++)
#pragma unroll
    for (int j = 0; j < 4; j++) mm[i * 4 + j] = my[i] * mx_[j];

  for (int g = 0; g < 8; g++) {
    const int co0 = g * 8;
    float acc[8][4];
#pragma unroll
    for (int m = 0; m < 8; m++)
#pragma unroll
      for (int q = 0; q < 4; q++) acc[m][q] = 0.f;
#pragma unroll
    for (int ci = 0; ci < 3; ci++) {
      float pv[16];
#pragma unroll
      for (int i = 0; i < 4; i++)
#pragma unroll
        for (int j = 0; j < 4; j++)
          pv[i * 4 + j] = xb[ci * 1024 + ry[i] + cx[j]] * mm[i * 4 + j];
#pragma unroll
      for (int m = 0; m < 8; m++) {
        const float* wr = w1e + (co0 + m) * 27 + ci * 9;
#pragma unroll
        for (int ky = 0; ky < 3; ky++)
#pragma unroll
          for (int kx = 0; kx < 3; kx++) {
            const float wv = wr[ky * 3 + kx];
#pragma unroll
            for (int dy = 0; dy < 2; dy++)
#pragma unroll
              for (int dx = 0; dx < 2; dx++)
                acc[m][dy * 2 + dx] += wv * pv[(ky + dy) * 4 + (kx + dx)];
          }
      }
    }
#pragma unroll
    for (int m = 0; m < 8; m++) {
      float v = fmaxf(fmaxf(acc[m][0], acc[m][1]), fmaxf(acc[m][2], acc[m][3]));
      v = fmaxf(v + b1e[co0 + m], 0.f);
      h1b[(co0 + m) * 256 + pos] = v;
    }
  }
}

// ---------------- K4b: expert conv2(64->128)+relu+pool -> h2[B,8192] -------
__global__ __launch_bounds__(256, 2) void k_conv2(
    const float* __restrict__ h1ws, const float* __restrict__ w2,
    const float* __restrict__ b2, const int* __restrict__ best_idx,
    float* __restrict__ h2ws) {
  const int b = blockIdx.x;
  const int tid = threadIdx.x;
  const int wave = __builtin_amdgcn_readfirstlane(tid >> 6);
  const int lane = tid & 63;
  const int e = __builtin_amdgcn_readfirstlane(best_idx[b]);
  const int py = lane >> 3, px = lane & 7;  // pooled pos in 8x8
  const int co0 = wave * 32;
  const float* h1b = h1ws + (size_t)b * 16384;
  const float* w2e = w2 + (size_t)e * 73728;

  int ry[4], cx[4];
  float my[4], mx_[4];
#pragma unroll
  for (int i = 0; i < 4; i++) {
    const int yy = 2 * py - 1 + i;
    my[i] = (yy >= 0 && yy < 16) ? 1.f : 0.f;
    ry[i] = min(max(yy, 0), 15) * 16;
    const int xx = 2 * px - 1 + i;
    mx_[i] = (xx >= 0 && xx < 16) ? 1.f : 0.f;
    cx[i] = min(max(xx, 0), 15);
  }
  float mm[16];
#pragma unroll
  for (int i = 0; i < 4; i++)
#pragma unroll
    for (int j = 0; j < 4; j++) mm[i * 4 + j] = my[i] * mx_[j];

  float acc[32][4];
#pragma unroll
  for (int m = 0; m < 32; m++)
#pragma unroll
    for (int q = 0; q < 4; q++) acc[m][q] = 0.f;

  for (int ci = 0; ci < 64; ci++) {
    float pv[16];
#pragma unroll
    for (int i = 0; i < 4; i++)
#pragma unroll
      for (int j = 0; j < 4; j++)
        pv[i * 4 + j] = h1b[ci * 256 + ry[i] + cx[j]] * mm[i * 4 + j];
#pragma unroll
    for (int m = 0; m < 32; m++) {
      const float* wr = w2e + (co0 + m) * 576 + ci * 9;
#pragma unroll
      for (int ky = 0; ky < 3; ky++)
#pragma unroll
        for (int kx = 0; kx < 3; kx++) {
          const float wv = wr[ky * 3 + kx];
#pragma unroll
          for (int dy = 0; dy < 2; dy++)
#pragma unroll
            for (int dx = 0; dx < 2; dx++)
              acc[m][dy * 2 + dx] += wv * pv[(ky + dy) * 4 + (kx + dx)];
        }
    }
  }

#pragma unroll
  for (int m = 0; m < 32; m++) {
    float v = fmaxf(fmaxf(acc[m][0], acc[m][1]), fmaxf(acc[m][2], acc[m][3]));
    v = fmaxf(v + b2[e * 128 + co0 + m], 0.f);
    h2ws[(size_t)b * 8192 + (co0 + m) * 64 + lane] = v;
  }
}

// ---------------- K5: FC GEMM, expert-grouped tiles, split-K=32 ------------
// Grid (36, 32). Block 256. Thread = 4 samples x 4 outputs register block.
// A addresses wave-deduplicated (2 transactions/instr); B rows L1/L2-reused.
__global__ __launch_bounds__(256) void k_fc(
    const float* __restrict__ h2ws, const float* __restrict__ efw,
    const float* __restrict__ efb, const int* __restrict__ order,
    const int* __restrict__ off, const int* __restrict__ counts,
    const float* __restrict__ best_w, float* __restrict__ out) {
  const int tix = blockIdx.x;  // sample tile of 32
  const int ks = blockIdx.y;   // K-chunk of 256
  const int base = tix * 32;
  if (base >= off[4]) return;
  int e = 0;
#pragma unroll
  for (int i = 1; i < 4; i++) if (base >= off[i]) e = i;
  const int vend = off[e] + counts[e];

  __shared__ int sid[32];
  __shared__ float sbw[32];
  const int t = threadIdx.x;
  if (t < 32) {
    const int pos = base + t;
    const bool v = pos < vend;
    const int s = v ? order[pos] : 0;
    sid[t] = v ? s : -1;
    sbw[t] = v ? best_w[s] : 0.f;
  }
  __syncthreads();

  const int rg = t >> 5;  // 0..7 -> rows rg*4..rg*4+3
  const int og = t & 31;  // active if < 25 -> outputs og + 25*j
  if (og >= 25) return;   // no further barriers below

  int s4[4];
  float bw4[4];
  bool v4[4];
  const float* a4[4];
#pragma unroll
  for (int i = 0; i < 4; i++) {
    const int r = rg * 4 + i;
    const int s = sid[r];
    v4[i] = (s >= 0);
    s4[i] = v4[i] ? s : 0;
    bw4[i] = sbw[r];
    a4[i] = h2ws + (size_t)s4[i] * 8192 + ks * FC_CHUNK;
  }
  const float* b4[4];
#pragma unroll
  for (int j = 0; j < 4; j++) {
    const int o = og + 25 * j;
    b4[j] = efw + (size_t)e * 819200 + (size_t)o * 8192 + ks * FC_CHUNK;
  }

  float acc[4][4];
#pragma unroll
  for (int i = 0; i < 4; i++)
#pragma unroll
    for (int j = 0; j < 4; j++) acc[i][j] = 0.f;

  for (int k = 0; k < FC_CHUNK; k += 4) {
    float4 av[4], bv[4];
#pragma unroll
    for (int i = 0; i < 4; i++) av[i] = *(const float4*)(a4[i] + k);
#pragma unroll
    for (int j = 0; j < 4; j++) bv[j] = *(const float4*)(b4[j] + k);
#pragma unroll
    for (int i = 0; i < 4; i++)
#pragma unroll
      for (int j = 0; j < 4; j++) {
        acc[i][j] += av[i].x * bv[j].x;
        acc[i][j] += av[i].y * bv[j].y;
        acc[i][j] += av[i].z * bv[j].z;
        acc[i][j] += av[i].w * bv[j].w;
      }
  }

#pragma unroll
  for (int i = 0; i < 4; i++) {
    if (!v4[i]) continue;
#pragma unroll
    for (int j = 0; j < 4; j++) {
      const int o = og + 25 * j;
      float v = acc[i][j] * bw4[i];
      if (ks == 0) v += efb[e * 100 + o] * bw4[i];
      atomicAdd(out + (size_t)s4[i] * 100 + o, v);
    }
  }
}

// ---------------------------------------------------------------------------
extern "C" void kernel_launch(void* const* d_in, const int* in_sizes, int n_in,
                              void* d_out, int out_size, void* d_ws, size_t ws_size,
                              hipStream_t stream) {
  const float* x   = (const float*)d_in[0];
  const float* gcw = (const float*)d_in[1];
  const float* gcb = (const float*)d_in[2];
  const float* gfw = (const float*)d_in[3];
  const float* gfb = (const float*)d_in[4];
  const float* c1w = (const float*)d_in[5];
  const float* c1b = (const float*)d_in[6];
  const float* c2w = (const float*)d_in[7];
  const float* c2b = (const float*)d_in[8];
  const float* efw = (const float*)d_in[9];
  const float* efb = (const float*)d_in[10];
  float* out = (float*)d_out;
  float* ws  = (float*)d_ws;

  // ws layout (float elements)
  float* g_mean  = ws;                      // 16384
  float* best_w  = ws + 16384;              // 1024
  int*   best_idx = (int*)(ws + 17408);     // 1024
  int*   counts   = (int*)(ws + 18432);     // 4
  int*   cnt2     = (int*)(ws + 18436);     // 4
  int*   off      = (int*)(ws + 18440);     // 5
  int*   order    = (int*)(ws + 18448);     // 1152
  float* h1 = ws + 20480;                   // 1024*64*16*16 = 16777216
  float* h2 = ws + 16797696;                // 1024*8192     = 8388608

  float* probs = out + 102400;
  float* aux   = out + 106496;

  hipMemsetAsync(out, 0, 102400 * sizeof(float), stream);  // atomic target
  hipMemsetAsync(counts, 0, 8 * sizeof(int), stream);      // counts + cnt2

  k_gate<<<1024, 256, 0, stream>>>(x, gcw, gcb, g_mean);
  k_router<<<4, 256, 0, stream>>>(g_mean, gfw, gfb, probs, best_w, best_idx, counts);
  k_offsets<<<1, 64, 0, stream>>>(counts, off);
  k_scatter<<<4, 256, 0, stream>>>(best_idx, off, cnt2, order);
  k_aux<<<1, 256, 0, stream>>>(probs, aux);
  k_conv1<<<1024, 256, 0, stream>>>(x, c1w, c1b, best_idx, h1);
  k_conv2<<<1024, 256, 0, stream>>>(h1, c2w, c2b, best_idx, h2);
  dim3 g5(36, FC_KS);
  k_fc<<<g5, 256, 0, stream>>>(h2, efw, efb, order, off, counts, best_w, out);
}

// Round 3
// 582.885 us; speedup vs baseline: 4.4654x; 2.3800x over previous
//
#include <hip/hip_runtime.h>
#include <hip/hip_bf16.h>
#include <cstdint>

// ---------------------------------------------------------------------------
// MoE CNN, hard top-1 dispatch. Round 3: conv2 -> bf16 MFMA implicit GEMM.
// Sizes: B=1024, Cin=3, HW=32, GC=16, E=4, C1=64, C2=128, FC_IN=8192, NC=100
// Output: [final 1024*100][probs 1024*4][aux 1]
// ---------------------------------------------------------------------------

#define B_TOT 1024
#define FC_KS 32
#define FC_CHUNK 256  // 8192 / FC_KS

typedef __attribute__((ext_vector_type(8))) short short8;
typedef __attribute__((ext_vector_type(16))) float f32x16;

__device__ __forceinline__ ushort f2bf(float f) {
  uint32_t u = __float_as_uint(f);
  u += 0x7fffu + ((u >> 16) & 1u);  // round-to-nearest-even
  return (ushort)(u >> 16);
}

// ---------------- K0: w2 fp32 [e][cout][ci][3][3] -> bf16 [e][kk][cout][ci] -
__global__ __launch_bounds__(256) void k_wprep(const float* __restrict__ w2,
                                               ushort* __restrict__ wp) {
  const int i = blockIdx.x * 256 + threadIdx.x;  // 294912 total
  const int ci = i & 63;
  const int cout = (i >> 6) & 127;
  const int kkE = i >> 13;          // e*9 + kk, 0..35
  const int kk = kkE - (kkE / 9) * 9;
  const int e = kkE / 9;
  const float f = w2[(size_t)(((e * 128 + cout) * 64 + ci) * 9) + kk];
  wp[i] = f2bf(f);
}

// ---------------- K1: gate conv(3->16,3x3 SAME)+relu+gap -> g_mean[B,16] ----
__global__ __launch_bounds__(256) void k_gate(
    const float* __restrict__ x, const float* __restrict__ gcw,
    const float* __restrict__ gcb, float* __restrict__ g_mean) {
  const int b = blockIdx.x;
  const int tid = threadIdx.x;
  const int wave = tid >> 6, lane = tid & 63;
  const float* xb = x + (size_t)b * 3072;

  float sums[16];
#pragma unroll
  for (int c = 0; c < 16; c++) sums[c] = 0.f;

  for (int k = 0; k < 4; k++) {
    const int p = tid + 256 * k;
    const int y = p >> 5, xx = p & 31;
    float acc[16];
#pragma unroll
    for (int c = 0; c < 16; c++) acc[c] = 0.f;
#pragma unroll
    for (int ci = 0; ci < 3; ci++) {
      float pv[9];
#pragma unroll
      for (int ky = 0; ky < 3; ky++)
#pragma unroll
        for (int kx = 0; kx < 3; kx++) {
          const int iy = y + ky - 1, ix = xx + kx - 1;
          const bool ok = (iy >= 0) && (iy < 32) && (ix >= 0) && (ix < 32);
          const int iyc = min(max(iy, 0), 31), ixc = min(max(ix, 0), 31);
          const float v = xb[ci * 1024 + iyc * 32 + ixc];
          pv[ky * 3 + kx] = ok ? v : 0.f;
        }
#pragma unroll
      for (int c = 0; c < 16; c++)
#pragma unroll
        for (int t = 0; t < 9; t++)
          acc[c] += pv[t] * gcw[(c * 3 + ci) * 9 + t];
    }
#pragma unroll
    for (int c = 0; c < 16; c++) sums[c] += fmaxf(acc[c] + gcb[c], 0.f);
  }

  __shared__ float red[4 * 16];
#pragma unroll
  for (int c = 0; c < 16; c++) {
    float v = sums[c];
    for (int o = 32; o > 0; o >>= 1) v += __shfl_down(v, o);
    if (lane == 0) red[wave * 16 + c] = v;
  }
  __syncthreads();
  if (tid < 16) {
    const float tot = red[tid] + red[16 + tid] + red[32 + tid] + red[48 + tid];
    g_mean[b * 16 + tid] = tot * (1.f / 1024.f);
  }
}

// ---------------- K2: router linear+softmax, argmax, counts ----------------
__global__ __launch_bounds__(256) void k_router(
    const float* __restrict__ g_mean, const float* __restrict__ gfw,
    const float* __restrict__ gfb, float* __restrict__ probs,
    float* __restrict__ best_w, int* __restrict__ best_idx,
    int* __restrict__ counts) {
  const int b = blockIdx.x * 256 + threadIdx.x;
  float g[16];
#pragma unroll
  for (int c = 0; c < 16; c++) g[c] = g_mean[b * 16 + c];
  float lg[4];
#pragma unroll
  for (int e = 0; e < 4; e++) {
    float s = gfb[e];
#pragma unroll
    for (int c = 0; c < 16; c++) s += g[c] * gfw[e * 16 + c];
    lg[e] = s;
  }
  float m = fmaxf(fmaxf(lg[0], lg[1]), fmaxf(lg[2], lg[3]));
  float ex[4], s = 0.f;
#pragma unroll
  for (int e = 0; e < 4; e++) { ex[e] = expf(lg[e] - m); s += ex[e]; }
  const float inv = 1.f / s;
  float p[4];
#pragma unroll
  for (int e = 0; e < 4; e++) { p[e] = ex[e] * inv; probs[b * 4 + e] = p[e]; }
  int bi = 0; float bp = p[0];
#pragma unroll
  for (int e = 1; e < 4; e++) if (p[e] > bp) { bp = p[e]; bi = e; }
  best_w[b] = bp;
  best_idx[b] = bi;
  atomicAdd(&counts[bi], 1);
}

// ---------------- K2c: 32-aligned segment offsets --------------------------
__global__ void k_offsets(const int* __restrict__ counts, int* __restrict__ off) {
  if (threadIdx.x == 0) {
    int o = 0;
    for (int e = 0; e < 4; e++) { off[e] = o; o += ((counts[e] + 31) & ~31); }
    off[4] = o;
  }
}

// ---------------- K2d: scatter sample ids grouped by expert ----------------
__global__ __launch_bounds__(256) void k_scatter(
    const int* __restrict__ best_idx, const int* __restrict__ off,
    int* __restrict__ cnt2, int* __restrict__ order) {
  const int b = blockIdx.x * 256 + threadIdx.x;
  const int e = best_idx[b];
  const int slot = off[e] + atomicAdd(&cnt2[e], 1);
  order[slot] = b;
}

// ---------------- K3: aux loss ---------------------------------------------
__global__ __launch_bounds__(256) void k_aux(const float* __restrict__ probs,
                                             float* __restrict__ aux_out) {
  __shared__ float red[16];
  const int t = threadIdx.x;
  const int wave = t >> 6, lane = t & 63;
  float sums[4] = {0.f, 0.f, 0.f, 0.f};
  for (int b = t; b < B_TOT; b += 256) {
#pragma unroll
    for (int e = 0; e < 4; e++) sums[e] += probs[b * 4 + e];
  }
#pragma unroll
  for (int e = 0; e < 4; e++) {
    float v = sums[e];
    for (int o = 32; o > 0; o >>= 1) v += __shfl_down(v, o);
    if (lane == 0) red[wave * 4 + e] = v;
  }
  __syncthreads();
  if (t == 0) {
    float aux = 0.f;
#pragma unroll
    for (int e = 0; e < 4; e++) {
      const float mp = (red[e] + red[4 + e] + red[8 + e] + red[12 + e]) * (1.f / 1024.f);
      const float d = mp - 0.25f;
      aux += d * d;
    }
    aux_out[0] = aux * 0.25f;
  }
}

// ---------------- K4: expert conv1(3->64)+relu+pool -> h1 bf16 [b][pos][ci] -
__global__ __launch_bounds__(256, 2) void k_conv1(
    const float* __restrict__ x, const float* __restrict__ w1,
    const float* __restrict__ b1, const int* __restrict__ best_idx,
    ushort* __restrict__ h1q) {
  const int b = blockIdx.x;
  const int tid = threadIdx.x;
  const int wave = __builtin_amdgcn_readfirstlane(tid >> 6);
  const int lane = tid & 63;
  const int e = __builtin_amdgcn_readfirstlane(best_idx[b]);
  const int pos = wave * 64 + lane;  // pooled position 0..255
  const int py = pos >> 4, px = pos & 15;
  const float* xb = x + (size_t)b * 3072;
  const float* w1e = w1 + (size_t)e * 1728;
  const float* b1e = b1 + (size_t)e * 64;
  ushort* h1b = h1q + (size_t)b * 16384;

  int ry[4], cx[4];
  float my[4], mx_[4];
#pragma unroll
  for (int i = 0; i < 4; i++) {
    const int yy = 2 * py - 1 + i;
    my[i] = (yy >= 0 && yy < 32) ? 1.f : 0.f;
    ry[i] = min(max(yy, 0), 31) * 32;
    const int xx = 2 * px - 1 + i;
    mx_[i] = (xx >= 0 && xx < 32) ? 1.f : 0.f;
    cx[i] = min(max(xx, 0), 31);
  }
  float mm[16];
#pragma unroll
  for (int i = 0; i < 4; i++)
#pragma unroll
    for (int j = 0; j < 4; j++) mm[i * 4 + j] = my[i] * mx_[j];

  for (int g = 0; g < 8; g++) {
    const int co0 = g * 8;
    float acc[8][4];
#pragma unroll
    for (int m = 0; m < 8; m++)
#pragma unroll
      for (int q = 0; q < 4; q++) acc[m][q] = 0.f;
#pragma unroll
    for (int ci = 0; ci < 3; ci++) {
      float pv[16];
#pragma unroll
      for (int i = 0; i < 4; i++)
#pragma unroll
        for (int j = 0; j < 4; j++)
          pv[i * 4 + j] = xb[ci * 1024 + ry[i] + cx[j]] * mm[i * 4 + j];
#pragma unroll
      for (int m = 0; m < 8; m++) {
        const float* wr = w1e + (co0 + m) * 27 + ci * 9;
#pragma unroll
        for (int ky = 0; ky < 3; ky++)
#pragma unroll
          for (int kx = 0; kx < 3; kx++) {
            const float wv = wr[ky * 3 + kx];
#pragma unroll
            for (int dy = 0; dy < 2; dy++)
#pragma unroll
              for (int dx = 0; dx < 2; dx++)
                acc[m][dy * 2 + dx] += wv * pv[(ky + dy) * 4 + (kx + dx)];
          }
      }
    }
    union { ushort us[8]; uint4 u4; } pk;
#pragma unroll
    for (int m = 0; m < 8; m++) {
      float v = fmaxf(fmaxf(acc[m][0], acc[m][1]), fmaxf(acc[m][2], acc[m][3]));
      v = fmaxf(v + b1e[co0 + m], 0.f);
      pk.us[m] = f2bf(v);
    }
    *(uint4*)(h1b + pos * 64 + co0) = pk.u4;  // 16B packed, ci-contiguous
  }
}

// ---------------- K4b: conv2 via bf16 MFMA implicit GEMM -------------------
// Grid 4096 = 1024 samples x 4 row-strips (4 out rows each). Block 256.
// Wave w: cout 32w..32w+31, all 64 spatial of strip (2 n-tiles of 2x16).
// K = 9 taps x 64 ci; mfma_f32_32x32x16_bf16; fused maxpool+bias+relu.
__global__ __launch_bounds__(256) void k_conv2(
    const ushort* __restrict__ h1q, const ushort* __restrict__ wp,
    const float* __restrict__ b2, const int* __restrict__ best_idx,
    float* __restrict__ h2) {
  __shared__ uint4 st[864];   // [row 6][cig 8][col 18] x 16B (8 ci bf16)
  __shared__ float pl[2048];  // [coutL 128][pooled 16]
  const int blk = blockIdx.x;
  const int b = blk >> 2;
  const int yq = blk & 3;  // out rows yq*4 .. yq*4+3
  const int t = threadIdx.x;
  const int e = __builtin_amdgcn_readfirstlane(best_idx[b]);

  // stage h1 rows yq*4-1 .. yq*4+4 (zero-padded) into LDS
  for (int c = t; c < 864; c += 256) {
    const int row = c / 144;           // 8*18
    const int rem = c - row * 144;
    const int cig = rem / 18;
    const int col = rem - cig * 18;
    const int gy = yq * 4 - 1 + row;
    uint4 v = make_uint4(0u, 0u, 0u, 0u);
    if (gy >= 0 && gy < 16 && col >= 1 && col <= 16)
      v = *(const uint4*)(h1q + ((size_t)b * 256 + gy * 16 + col - 1) * 64 + cig * 8);
    st[c] = v;  // c == (row*8+cig)*18+col
  }
  __syncthreads();

  const int wv = t >> 6;
  const int lane = t & 63;
  const int n = lane & 31;        // spatial within n-tile: (n>>4)=drow, (n&15)=col
  const int half = lane >> 5;     // k-half: ci offset half*8
  const int drow = n >> 4;
  const int col = n & 15;
  const int cout0 = wv * 32;

  f32x16 acc0, acc1;
#pragma unroll
  for (int i = 0; i < 16; i++) { acc0[i] = 0.f; acc1[i] = 0.f; }

  const ushort* wpa = wp + (size_t)e * 73728 + (size_t)(cout0 + n) * 64 + half * 8;
  const short* sb = (const short*)st;

  for (int kk = 0; kk < 9; kk++) {
    const int ky = kk / 3;
    const int kx = kk - ky * 3;
#pragma unroll
    for (int c4 = 0; c4 < 4; c4++) {
      const int ci0 = c4 * 16;
      const int cig = c4 * 2 + half;
      const short8 af = *(const short8*)(wpa + kk * 8192 + ci0);
      const short8 bf0 = *(const short8*)(sb + (((drow + ky) * 8 + cig) * 18 + col + kx) * 8);
      const short8 bf1 = *(const short8*)(sb + (((2 + drow + ky) * 8 + cig) * 18 + col + kx) * 8);
      acc0 = __builtin_amdgcn_mfma_f32_32x32x16_bf16(af, bf0, acc0, 0, 0, 0);
      acc1 = __builtin_amdgcn_mfma_f32_32x32x16_bf16(af, bf1, acc1, 0, 0, 0);
    }
  }

  // fused 2x2 maxpool: cols via shfl_xor(1), rows via shfl_xor(16)
#pragma unroll
  for (int tt = 0; tt < 2; tt++) {
    const f32x16 a = tt ? acc1 : acc0;
#pragma unroll
    for (int r = 0; r < 16; r++) {
      float v = a[r];
      v = fmaxf(v, __shfl_xor(v, 1));
      v = fmaxf(v, __shfl_xor(v, 16));
      if ((lane & 17) == 0) {  // n even, drow==0
        const int rowm = (r & 3) + 8 * (r >> 2) + 4 * half;
        const int pc = n >> 1;  // 0..7
        pl[(cout0 + rowm) * 16 + tt * 8 + pc] = v;
      }
    }
  }
  __syncthreads();

  // bias + relu + coalesced write: h2[b][cout][yq*16 + p], p in 0..15
  {
    const int coutL = t >> 1;
    const int hh = t & 1;
    const float bias = b2[e * 128 + coutL];
    const float* src = pl + coutL * 16 + hh * 8;
    float4 o0, o1;
    o0.x = fmaxf(src[0] + bias, 0.f);
    o0.y = fmaxf(src[1] + bias, 0.f);
    o0.z = fmaxf(src[2] + bias, 0.f);
    o0.w = fmaxf(src[3] + bias, 0.f);
    o1.x = fmaxf(src[4] + bias, 0.f);
    o1.y = fmaxf(src[5] + bias, 0.f);
    o1.z = fmaxf(src[6] + bias, 0.f);
    o1.w = fmaxf(src[7] + bias, 0.f);
    float* dst = h2 + (size_t)b * 8192 + coutL * 64 + yq * 16 + hh * 8;
    *(float4*)dst = o0;
    *(float4*)(dst + 4) = o1;
  }
}

// ---------------- K5: FC GEMM, expert-grouped tiles, split-K=32 ------------
__global__ __launch_bounds__(256) void k_fc(
    const float* __restrict__ h2ws, const float* __restrict__ efw,
    const float* __restrict__ efb, const int* __restrict__ order,
    const int* __restrict__ off, const int* __restrict__ counts,
    const float* __restrict__ best_w, float* __restrict__ out) {
  const int tix = blockIdx.x;  // sample tile of 32
  const int ks = blockIdx.y;   // K-chunk of 256
  const int base = tix * 32;
  if (base >= off[4]) return;
  int e = 0;
#pragma unroll
  for (int i = 1; i < 4; i++) if (base >= off[i]) e = i;
  const int vend = off[e] + counts[e];

  __shared__ int sid[32];
  __shared__ float sbw[32];
  const int t = threadIdx.x;
  if (t < 32) {
    const int pos = base + t;
    const bool v = pos < vend;
    const int s = v ? order[pos] : 0;
    sid[t] = v ? s : -1;
    sbw[t] = v ? best_w[s] : 0.f;
  }
  __syncthreads();

  const int rg = t >> 5;  // 0..7 -> rows rg*4..rg*4+3
  const int og = t & 31;  // active if < 25 -> outputs og + 25*j
  if (og >= 25) return;

  int s4[4];
  float bw4[4];
  bool v4[4];
  const float* a4[4];
#pragma unroll
  for (int i = 0; i < 4; i++) {
    const int r = rg * 4 + i;
    const int s = sid[r];
    v4[i] = (s >= 0);
    s4[i] = v4[i] ? s : 0;
    bw4[i] = sbw[r];
    a4[i] = h2ws + (size_t)s4[i] * 8192 + ks * FC_CHUNK;
  }
  const float* b4[4];
#pragma unroll
  for (int j = 0; j < 4; j++) {
    const int o = og + 25 * j;
    b4[j] = efw + (size_t)e * 819200 + (size_t)o * 8192 + ks * FC_CHUNK;
  }

  float acc[4][4];
#pragma unroll
  for (int i = 0; i < 4; i++)
#pragma unroll
    for (int j = 0; j < 4; j++) acc[i][j] = 0.f;

  for (int k = 0; k < FC_CHUNK; k += 4) {
    float4 av[4], bv[4];
#pragma unroll
    for (int i = 0; i < 4; i++) av[i] = *(const float4*)(a4[i] + k);
#pragma unroll
    for (int j = 0; j < 4; j++) bv[j] = *(const float4*)(b4[j] + k);
#pragma unroll
    for (int i = 0; i < 4; i++)
#pragma unroll
      for (int j = 0; j < 4; j++) {
        acc[i][j] += av[i].x * bv[j].x;
        acc[i][j] += av[i].y * bv[j].y;
        acc[i][j] += av[i].z * bv[j].z;
        acc[i][j] += av[i].w * bv[j].w;
      }
  }

#pragma unroll
  for (int i = 0; i < 4; i++) {
    if (!v4[i]) continue;
#pragma unroll
    for (int j = 0; j < 4; j++) {
      const int o = og + 25 * j;
      float v = acc[i][j] * bw4[i];
      if (ks == 0) v += efb[e * 100 + o] * bw4[i];
      atomicAdd(out + (size_t)s4[i] * 100 + o, v);
    }
  }
}

// ---------------------------------------------------------------------------
extern "C" void kernel_launch(void* const* d_in, const int* in_sizes, int n_in,
                              void* d_out, int out_size, void* d_ws, size_t ws_size,
                              hipStream_t stream) {
  const float* x   = (const float*)d_in[0];
  const float* gcw = (const float*)d_in[1];
  const float* gcb = (const float*)d_in[2];
  const float* gfw = (const float*)d_in[3];
  const float* gfb = (const float*)d_in[4];
  const float* c1w = (const float*)d_in[5];
  const float* c1b = (const float*)d_in[6];
  const float* c2w = (const float*)d_in[7];
  const float* c2b = (const float*)d_in[8];
  const float* efw = (const float*)d_in[9];
  const float* efb = (const float*)d_in[10];
  float* out = (float*)d_out;
  float* ws  = (float*)d_ws;

  // ws layout (float-element offsets)
  float*  g_mean   = ws;                        // 16384
  float*  best_w   = ws + 16384;                // 1024
  int*    best_idx = (int*)(ws + 17408);        // 1024
  int*    counts   = (int*)(ws + 18432);        // 4
  int*    cnt2     = (int*)(ws + 18436);        // 4
  int*    off      = (int*)(ws + 18440);        // 5
  int*    order    = (int*)(ws + 18448);        // 1152
  ushort* wp       = (ushort*)(ws + 20480);     // 294912 bf16 -> 147456 f
  ushort* h1       = (ushort*)(ws + 167936);    // 16777216 bf16 -> 8388608 f
  float*  h2       = ws + 8556544;              // 8388608 f

  float* probs = out + 102400;
  float* aux   = out + 106496;

  hipMemsetAsync(out, 0, 102400 * sizeof(float), stream);  // atomic target
  hipMemsetAsync(counts, 0, 8 * sizeof(int), stream);      // counts + cnt2

  k_wprep<<<1152, 256, 0, stream>>>(c2w, wp);
  k_gate<<<1024, 256, 0, stream>>>(x, gcw, gcb, g_mean);
  k_router<<<4, 256, 0, stream>>>(g_mean, gfw, gfb, probs, best_w, best_idx, counts);
  k_offsets<<<1, 64, 0, stream>>>(counts, off);
  k_scatter<<<4, 256, 0, stream>>>(best_idx, off, cnt2, order);
  k_aux<<<1, 256, 0, stream>>>(probs, aux);
  k_conv1<<<1024, 256, 0, stream>>>(x, c1w, c1b, best_idx, h1);
  k_conv2<<<4096, 256, 0, stream>>>(h1, wp, c2b, best_idx, h2);
  dim3 g5(36, FC_KS);
  k_fc<<<g5, 256, 0, stream>>>(h2, efw, efb, order, off, counts, best_w, out);
}

// Round 4
// 438.034 us; speedup vs baseline: 5.9421x; 1.3307x over previous
//
#include <hip/hip_runtime.h>
#include <hip/hip_bf16.h>
#include <cstdint>

// ---------------------------------------------------------------------------
// MoE CNN, hard top-1 dispatch. Round 4: k_gate -> LDS-halo maskless conv.
// Sizes: B=1024, Cin=3, HW=32, GC=16, E=4, C1=64, C2=128, FC_IN=8192, NC=100
// Output: [final 1024*100][probs 1024*4][aux 1]
// ---------------------------------------------------------------------------

#define B_TOT 1024
#define FC_KS 32
#define FC_CHUNK 256  // 8192 / FC_KS

typedef __attribute__((ext_vector_type(8))) short short8;
typedef __attribute__((ext_vector_type(16))) float f32x16;

__device__ __forceinline__ ushort f2bf(float f) {
  uint32_t u = __float_as_uint(f);
  u += 0x7fffu + ((u >> 16) & 1u);  // round-to-nearest-even
  return (ushort)(u >> 16);
}

// ---------------- K0: w2 fp32 [e][cout][ci][3][3] -> bf16 [e][kk][cout][ci] -
__global__ __launch_bounds__(256) void k_wprep(const float* __restrict__ w2,
                                               ushort* __restrict__ wp) {
  const int i = blockIdx.x * 256 + threadIdx.x;  // 294912 total
  const int ci = i & 63;
  const int cout = (i >> 6) & 127;
  const int kkE = i >> 13;          // e*9 + kk, 0..35
  const int kk = kkE - (kkE / 9) * 9;
  const int e = kkE / 9;
  const float f = w2[(size_t)(((e * 128 + cout) * 64 + ci) * 9) + kk];
  wp[i] = f2bf(f);
}

// ---------------- K1: gate conv(3->16)+relu+gap, LDS halo, maskless --------
// Block per sample. x staged as zero-padded [3][34][34]. Thread = 4 px in row.
__global__ __launch_bounds__(256, 4) void k_gate(
    const float* __restrict__ x, const float* __restrict__ gcw,
    const float* __restrict__ gcb, float* __restrict__ g_mean) {
  __shared__ float xs[3 * 34 * 34];  // 13872 B zero-padded halo
  __shared__ float red[4 * 16];
  const int b = blockIdx.x;
  const int t = threadIdx.x;
  const float* xb = x + (size_t)b * 3072;

  for (int c = t; c < 3468; c += 256) {
    const int ci = c / 1156;
    const int rem = c - ci * 1156;
    const int y = rem / 34;
    const int xx = rem - y * 34;
    const int gy = y - 1, gx = xx - 1;
    float v = 0.f;
    if (gy >= 0 && gy < 32 && gx >= 0 && gx < 32) v = xb[ci * 1024 + gy * 32 + gx];
    xs[c] = v;
  }
  __syncthreads();

  const int r = t >> 3;        // output row 0..31
  const int c0 = (t & 7) * 4;  // output col base 0,4,...,28

  float accp[16][4];
#pragma unroll
  for (int c = 0; c < 16; c++)
#pragma unroll
    for (int p = 0; p < 4; p++) accp[c][p] = 0.f;

#pragma unroll
  for (int ci = 0; ci < 3; ci++) {
    float pv[3][6];
#pragma unroll
    for (int dy = 0; dy < 3; dy++) {
      const float* row = xs + ci * 1156 + (r + dy) * 34 + c0;
#pragma unroll
      for (int dx = 0; dx < 6; dx++) pv[dy][dx] = row[dx];
    }
#pragma unroll
    for (int c = 0; c < 16; c++) {
      const float* wr = gcw + (c * 3 + ci) * 9;
#pragma unroll
      for (int ky = 0; ky < 3; ky++)
#pragma unroll
        for (int kx = 0; kx < 3; kx++) {
          const float wv = wr[ky * 3 + kx];
#pragma unroll
          for (int p = 0; p < 4; p++)
            accp[c][p] += wv * pv[ky][kx + p];
        }
    }
  }

  float sums[16];
#pragma unroll
  for (int c = 0; c < 16; c++) {
    const float bb = gcb[c];
    float s = 0.f;
#pragma unroll
    for (int p = 0; p < 4; p++) s += fmaxf(accp[c][p] + bb, 0.f);
    sums[c] = s;
  }

  const int wave = t >> 6, lane = t & 63;
#pragma unroll
  for (int c = 0; c < 16; c++) {
    float v = sums[c];
    for (int o = 32; o > 0; o >>= 1) v += __shfl_down(v, o);
    if (lane == 0) red[wave * 16 + c] = v;
  }
  __syncthreads();
  if (t < 16) {
    g_mean[b * 16 + t] =
        (red[t] + red[16 + t] + red[32 + t] + red[48 + t]) * (1.f / 1024.f);
  }
}

// ---------------- K2: router linear+softmax, argmax, counts ----------------
__global__ __launch_bounds__(256) void k_router(
    const float* __restrict__ g_mean, const float* __restrict__ gfw,
    const float* __restrict__ gfb, float* __restrict__ probs,
    float* __restrict__ best_w, int* __restrict__ best_idx,
    int* __restrict__ counts) {
  const int b = blockIdx.x * 256 + threadIdx.x;
  float g[16];
#pragma unroll
  for (int c = 0; c < 16; c++) g[c] = g_mean[b * 16 + c];
  float lg[4];
#pragma unroll
  for (int e = 0; e < 4; e++) {
    float s = gfb[e];
#pragma unroll
    for (int c = 0; c < 16; c++) s += g[c] * gfw[e * 16 + c];
    lg[e] = s;
  }
  float m = fmaxf(fmaxf(lg[0], lg[1]), fmaxf(lg[2], lg[3]));
  float ex[4], s = 0.f;
#pragma unroll
  for (int e = 0; e < 4; e++) { ex[e] = expf(lg[e] - m); s += ex[e]; }
  const float inv = 1.f / s;
  float p[4];
#pragma unroll
  for (int e = 0; e < 4; e++) { p[e] = ex[e] * inv; probs[b * 4 + e] = p[e]; }
  int bi = 0; float bp = p[0];
#pragma unroll
  for (int e = 1; e < 4; e++) if (p[e] > bp) { bp = p[e]; bi = e; }
  best_w[b] = bp;
  best_idx[b] = bi;
  atomicAdd(&counts[bi], 1);
}

// ---------------- K2c: 32-aligned segment offsets --------------------------
__global__ void k_offsets(const int* __restrict__ counts, int* __restrict__ off) {
  if (threadIdx.x == 0) {
    int o = 0;
    for (int e = 0; e < 4; e++) { off[e] = o; o += ((counts[e] + 31) & ~31); }
    off[4] = o;
  }
}

// ---------------- K2d: scatter sample ids grouped by expert ----------------
__global__ __launch_bounds__(256) void k_scatter(
    const int* __restrict__ best_idx, const int* __restrict__ off,
    int* __restrict__ cnt2, int* __restrict__ order) {
  const int b = blockIdx.x * 256 + threadIdx.x;
  const int e = best_idx[b];
  const int slot = off[e] + atomicAdd(&cnt2[e], 1);
  order[slot] = b;
}

// ---------------- K3: aux loss ---------------------------------------------
__global__ __launch_bounds__(256) void k_aux(const float* __restrict__ probs,
                                             float* __restrict__ aux_out) {
  __shared__ float red[16];
  const int t = threadIdx.x;
  const int wave = t >> 6, lane = t & 63;
  float sums[4] = {0.f, 0.f, 0.f, 0.f};
  for (int b = t; b < B_TOT; b += 256) {
#pragma unroll
    for (int e = 0; e < 4; e++) sums[e] += probs[b * 4 + e];
  }
#pragma unroll
  for (int e = 0; e < 4; e++) {
    float v = sums[e];
    for (int o = 32; o > 0; o >>= 1) v += __shfl_down(v, o);
    if (lane == 0) red[wave * 4 + e] = v;
  }
  __syncthreads();
  if (t == 0) {
    float aux = 0.f;
#pragma unroll
    for (int e = 0; e < 4; e++) {
      const float mp = (red[e] + red[4 + e] + red[8 + e] + red[12 + e]) * (1.f / 1024.f);
      const float d = mp - 0.25f;
      aux += d * d;
    }
    aux_out[0] = aux * 0.25f;
  }
}

// ---------------- K4: expert conv1(3->64)+relu+pool -> h1 bf16 [b][pos][ci] -
__global__ __launch_bounds__(256, 2) void k_conv1(
    const float* __restrict__ x, const float* __restrict__ w1,
    const float* __restrict__ b1, const int* __restrict__ best_idx,
    ushort* __restrict__ h1q) {
  const int b = blockIdx.x;
  const int tid = threadIdx.x;
  const int wave = __builtin_amdgcn_readfirstlane(tid >> 6);
  const int lane = tid & 63;
  const int e = __builtin_amdgcn_readfirstlane(best_idx[b]);
  const int pos = wave * 64 + lane;  // pooled position 0..255
  const int py = pos >> 4, px = pos & 15;
  const float* xb = x + (size_t)b * 3072;
  const float* w1e = w1 + (size_t)e * 1728;
  const float* b1e = b1 + (size_t)e * 64;
  ushort* h1b = h1q + (size_t)b * 16384;

  int ry[4], cx[4];
  float my[4], mx_[4];
#pragma unroll
  for (int i = 0; i < 4; i++) {
    const int yy = 2 * py - 1 + i;
    my[i] = (yy >= 0 && yy < 32) ? 1.f : 0.f;
    ry[i] = min(max(yy, 0), 31) * 32;
    const int xx = 2 * px - 1 + i;
    mx_[i] = (xx >= 0 && xx < 32) ? 1.f : 0.f;
    cx[i] = min(max(xx, 0), 31);
  }
  float mm[16];
#pragma unroll
  for (int i = 0; i < 4; i++)
#pragma unroll
    for (int j = 0; j < 4; j++) mm[i * 4 + j] = my[i] * mx_[j];

  for (int g = 0; g < 8; g++) {
    const int co0 = g * 8;
    float acc[8][4];
#pragma unroll
    for (int m = 0; m < 8; m++)
#pragma unroll
      for (int q = 0; q < 4; q++) acc[m][q] = 0.f;
#pragma unroll
    for (int ci = 0; ci < 3; ci++) {
      float pv[16];
#pragma unroll
      for (int i = 0; i < 4; i++)
#pragma unroll
        for (int j = 0; j < 4; j++)
          pv[i * 4 + j] = xb[ci * 1024 + ry[i] + cx[j]] * mm[i * 4 + j];
#pragma unroll
      for (int m = 0; m < 8; m++) {
        const float* wr = w1e + (co0 + m) * 27 + ci * 9;
#pragma unroll
        for (int ky = 0; ky < 3; ky++)
#pragma unroll
          for (int kx = 0; kx < 3; kx++) {
            const float wv = wr[ky * 3 + kx];
#pragma unroll
            for (int dy = 0; dy < 2; dy++)
#pragma unroll
              for (int dx = 0; dx < 2; dx++)
                acc[m][dy * 2 + dx] += wv * pv[(ky + dy) * 4 + (kx + dx)];
          }
      }
    }
    union { ushort us[8]; uint4 u4; } pk;
#pragma unroll
    for (int m = 0; m < 8; m++) {
      float v = fmaxf(fmaxf(acc[m][0], acc[m][1]), fmaxf(acc[m][2], acc[m][3]));
      v = fmaxf(v + b1e[co0 + m], 0.f);
      pk.us[m] = f2bf(v);
    }
    *(uint4*)(h1b + pos * 64 + co0) = pk.u4;  // 16B packed, ci-contiguous
  }
}

// ---------------- K4b: conv2 via bf16 MFMA implicit GEMM -------------------
__global__ __launch_bounds__(256) void k_conv2(
    const ushort* __restrict__ h1q, const ushort* __restrict__ wp,
    const float* __restrict__ b2, const int* __restrict__ best_idx,
    float* __restrict__ h2) {
  __shared__ uint4 st[864];   // [row 6][cig 8][col 18] x 16B (8 ci bf16)
  __shared__ float pl[2048];  // [coutL 128][pooled 16]
  const int blk = blockIdx.x;
  const int b = blk >> 2;
  const int yq = blk & 3;  // out rows yq*4 .. yq*4+3
  const int t = threadIdx.x;
  const int e = __builtin_amdgcn_readfirstlane(best_idx[b]);

  // stage h1 rows yq*4-1 .. yq*4+4 (zero-padded) into LDS
  for (int c = t; c < 864; c += 256) {
    const int row = c / 144;           // 8*18
    const int rem = c - row * 144;
    const int cig = rem / 18;
    const int col = rem - cig * 18;
    const int gy = yq * 4 - 1 + row;
    uint4 v = make_uint4(0u, 0u, 0u, 0u);
    if (gy >= 0 && gy < 16 && col >= 1 && col <= 16)
      v = *(const uint4*)(h1q + ((size_t)b * 256 + gy * 16 + col - 1) * 64 + cig * 8);
    st[c] = v;  // c == (row*8+cig)*18+col
  }
  __syncthreads();

  const int wv = t >> 6;
  const int lane = t & 63;
  const int n = lane & 31;        // spatial within n-tile
  const int half = lane >> 5;     // k-half: ci offset half*8
  const int drow = n >> 4;
  const int col = n & 15;
  const int cout0 = wv * 32;

  f32x16 acc0, acc1;
#pragma unroll
  for (int i = 0; i < 16; i++) { acc0[i] = 0.f; acc1[i] = 0.f; }

  const ushort* wpa = wp + (size_t)e * 73728 + (size_t)(cout0 + n) * 64 + half * 8;
  const short* sb = (const short*)st;

  for (int kk = 0; kk < 9; kk++) {
    const int ky = kk / 3;
    const int kx = kk - ky * 3;
#pragma unroll
    for (int c4 = 0; c4 < 4; c4++) {
      const int ci0 = c4 * 16;
      const int cig = c4 * 2 + half;
      const short8 af = *(const short8*)(wpa + kk * 8192 + ci0);
      const short8 bf0 = *(const short8*)(sb + (((drow + ky) * 8 + cig) * 18 + col + kx) * 8);
      const short8 bf1 = *(const short8*)(sb + (((2 + drow + ky) * 8 + cig) * 18 + col + kx) * 8);
      acc0 = __builtin_amdgcn_mfma_f32_32x32x16_bf16(af, bf0, acc0, 0, 0, 0);
      acc1 = __builtin_amdgcn_mfma_f32_32x32x16_bf16(af, bf1, acc1, 0, 0, 0);
    }
  }

  // fused 2x2 maxpool: cols via shfl_xor(1), rows via shfl_xor(16)
#pragma unroll
  for (int tt = 0; tt < 2; tt++) {
    const f32x16 a = tt ? acc1 : acc0;
#pragma unroll
    for (int r = 0; r < 16; r++) {
      float v = a[r];
      v = fmaxf(v, __shfl_xor(v, 1));
      v = fmaxf(v, __shfl_xor(v, 16));
      if ((lane & 17) == 0) {  // n even, drow==0
        const int rowm = (r & 3) + 8 * (r >> 2) + 4 * half;
        const int pc = n >> 1;  // 0..7
        pl[(cout0 + rowm) * 16 + tt * 8 + pc] = v;
      }
    }
  }
  __syncthreads();

  // bias + relu + coalesced write: h2[b][cout][yq*16 + p], p in 0..15
  {
    const int coutL = t >> 1;
    const int hh = t & 1;
    const float bias = b2[e * 128 + coutL];
    const float* src = pl + coutL * 16 + hh * 8;
    float4 o0, o1;
    o0.x = fmaxf(src[0] + bias, 0.f);
    o0.y = fmaxf(src[1] + bias, 0.f);
    o0.z = fmaxf(src[2] + bias, 0.f);
    o0.w = fmaxf(src[3] + bias, 0.f);
    o1.x = fmaxf(src[4] + bias, 0.f);
    o1.y = fmaxf(src[5] + bias, 0.f);
    o1.z = fmaxf(src[6] + bias, 0.f);
    o1.w = fmaxf(src[7] + bias, 0.f);
    float* dst = h2 + (size_t)b * 8192 + coutL * 64 + yq * 16 + hh * 8;
    *(float4*)dst = o0;
    *(float4*)(dst + 4) = o1;
  }
}

// ---------------- K5: FC GEMM, expert-grouped tiles, split-K=32 ------------
__global__ __launch_bounds__(256) void k_fc(
    const float* __restrict__ h2ws, const float* __restrict__ efw,
    const float* __restrict__ efb, const int* __restrict__ order,
    const int* __restrict__ off, const int* __restrict__ counts,
    const float* __restrict__ best_w, float* __restrict__ out) {
  const int tix = blockIdx.x;  // sample tile of 32
  const int ks = blockIdx.y;   // K-chunk of 256
  const int base = tix * 32;
  if (base >= off[4]) return;
  int e = 0;
#pragma unroll
  for (int i = 1; i < 4; i++) if (base >= off[i]) e = i;
  const int vend = off[e] + counts[e];

  __shared__ int sid[32];
  __shared__ float sbw[32];
  const int t = threadIdx.x;
  if (t < 32) {
    const int pos = base + t;
    const bool v = pos < vend;
    const int s = v ? order[pos] : 0;
    sid[t] = v ? s : -1;
    sbw[t] = v ? best_w[s] : 0.f;
  }
  __syncthreads();

  const int rg = t >> 5;  // 0..7 -> rows rg*4..rg*4+3
  const int og = t & 31;  // active if < 25 -> outputs og + 25*j
  if (og >= 25) return;

  int s4[4];
  float bw4[4];
  bool v4[4];
  const float* a4[4];
#pragma unroll
  for (int i = 0; i < 4; i++) {
    const int r = rg * 4 + i;
    const int s = sid[r];
    v4[i] = (s >= 0);
    s4[i] = v4[i] ? s : 0;
    bw4[i] = sbw[r];
    a4[i] = h2ws + (size_t)s4[i] * 8192 + ks * FC_CHUNK;
  }
  const float* b4[4];
#pragma unroll
  for (int j = 0; j < 4; j++) {
    const int o = og + 25 * j;
    b4[j] = efw + (size_t)e * 819200 + (size_t)o * 8192 + ks * FC_CHUNK;
  }

  float acc[4][4];
#pragma unroll
  for (int i = 0; i < 4; i++)
#pragma unroll
    for (int j = 0; j < 4; j++) acc[i][j] = 0.f;

  for (int k = 0; k < FC_CHUNK; k += 4) {
    float4 av[4], bv[4];
#pragma unroll
    for (int i = 0; i < 4; i++) av[i] = *(const float4*)(a4[i] + k);
#pragma unroll
    for (int j = 0; j < 4; j++) bv[j] = *(const float4*)(b4[j] + k);
#pragma unroll
    for (int i = 0; i < 4; i++)
#pragma unroll
      for (int j = 0; j < 4; j++) {
        acc[i][j] += av[i].x * bv[j].x;
        acc[i][j] += av[i].y * bv[j].y;
        acc[i][j] += av[i].z * bv[j].z;
        acc[i][j] += av[i].w * bv[j].w;
      }
  }

#pragma unroll
  for (int i = 0; i < 4; i++) {
    if (!v4[i]) continue;
#pragma unroll
    for (int j = 0; j < 4; j++) {
      const int o = og + 25 * j;
      float v = acc[i][j] * bw4[i];
      if (ks == 0) v += efb[e * 100 + o] * bw4[i];
      atomicAdd(out + (size_t)s4[i] * 100 + o, v);
    }
  }
}

// ---------------------------------------------------------------------------
extern "C" void kernel_launch(void* const* d_in, const int* in_sizes, int n_in,
                              void* d_out, int out_size, void* d_ws, size_t ws_size,
                              hipStream_t stream) {
  const float* x   = (const float*)d_in[0];
  const float* gcw = (const float*)d_in[1];
  const float* gcb = (const float*)d_in[2];
  const float* gfw = (const float*)d_in[3];
  const float* gfb = (const float*)d_in[4];
  const float* c1w = (const float*)d_in[5];
  const float* c1b = (const float*)d_in[6];
  const float* c2w = (const float*)d_in[7];
  const float* c2b = (const float*)d_in[8];
  const float* efw = (const float*)d_in[9];
  const float* efb = (const float*)d_in[10];
  float* out = (float*)d_out;
  float* ws  = (float*)d_ws;

  // ws layout (float-element offsets)
  float*  g_mean   = ws;                        // 16384
  float*  best_w   = ws + 16384;                // 1024
  int*    best_idx = (int*)(ws + 17408);        // 1024
  int*    counts   = (int*)(ws + 18432);        // 4
  int*    cnt2     = (int*)(ws + 18436);        // 4
  int*    off      = (int*)(ws + 18440);        // 5
  int*    order    = (int*)(ws + 18448);        // 1152
  ushort* wp       = (ushort*)(ws + 20480);     // 294912 bf16 -> 147456 f
  ushort* h1       = (ushort*)(ws + 167936);    // 16777216 bf16 -> 8388608 f
  float*  h2       = ws + 8556544;              // 8388608 f

  float* probs = out + 102400;
  float* aux   = out + 106496;

  hipMemsetAsync(out, 0, 102400 * sizeof(float), stream);  // atomic target
  hipMemsetAsync(counts, 0, 8 * sizeof(int), stream);      // counts + cnt2

  k_wprep<<<1152, 256, 0, stream>>>(c2w, wp);
  k_gate<<<1024, 256, 0, stream>>>(x, gcw, gcb, g_mean);
  k_router<<<4, 256, 0, stream>>>(g_mean, gfw, gfb, probs, best_w, best_idx, counts);
  k_offsets<<<1, 64, 0, stream>>>(counts, off);
  k_scatter<<<4, 256, 0, stream>>>(best_idx, off, cnt2, order);
  k_aux<<<1, 256, 0, stream>>>(probs, aux);
  k_conv1<<<1024, 256, 0, stream>>>(x, c1w, c1b, best_idx, h1);
  k_conv2<<<4096, 256, 0, stream>>>(h1, wp, c2b, best_idx, h2);
  dim3 g5(36, FC_KS);
  k_fc<<<g5, 256, 0, stream>>>(h2, efw, efb, order, off, counts, best_w, out);
}

// Round 5
// 386.000 us; speedup vs baseline: 6.7431x; 1.1348x over previous
//
#include <hip/hip_runtime.h>
#include <hip/hip_bf16.h>
#include <cstdint>

// ---------------------------------------------------------------------------
// MoE CNN, hard top-1 dispatch. Round 5: k_fc -> bf16 MFMA GEMM (h2 in bf16).
// Sizes: B=1024, Cin=3, HW=32, GC=16, E=4, C1=64, C2=128, FC_IN=8192, NC=100
// Output: [final 1024*100][probs 1024*4][aux 1]
// ---------------------------------------------------------------------------

#define B_TOT 1024

typedef __attribute__((ext_vector_type(8))) short short8;
typedef __attribute__((ext_vector_type(16))) float f32x16;

__device__ __forceinline__ ushort f2bf(float f) {
  uint32_t u = __float_as_uint(f);
  u += 0x7fffu + ((u >> 16) & 1u);  // round-to-nearest-even
  return (ushort)(u >> 16);
}

// ---------------- K0: w2 fp32 [e][cout][ci][3][3] -> bf16 [e][kk][cout][ci] -
__global__ __launch_bounds__(256) void k_wprep(const float* __restrict__ w2,
                                               ushort* __restrict__ wp) {
  const int i = blockIdx.x * 256 + threadIdx.x;  // 294912 total
  const int ci = i & 63;
  const int cout = (i >> 6) & 127;
  const int kkE = i >> 13;          // e*9 + kk, 0..35
  const int kk = kkE - (kkE / 9) * 9;
  const int e = kkE / 9;
  const float f = w2[(size_t)(((e * 128 + cout) * 64 + ci) * 9) + kk];
  wp[i] = f2bf(f);
}

// ---------------- K0b: efw fp32 [e][100][8192] -> bf16 [e][kb][cout128][8] -
__global__ __launch_bounds__(256) void k_wfc(const float* __restrict__ efw,
                                             ushort* __restrict__ wfc) {
  const int i = blockIdx.x * 256 + threadIdx.x;  // 4194304 total
  const int j = i & 7;
  const int cout = (i >> 3) & 127;
  const int kb = (i >> 10) & 1023;
  const int e = i >> 20;
  const int k = kb * 8 + j;
  float f = 0.f;
  if (cout < 100) f = efw[((size_t)(e * 100 + cout)) * 8192 + k];
  wfc[i] = f2bf(f);
}

// ---------------- K1: gate conv(3->16)+relu+gap, LDS halo, maskless --------
__global__ __launch_bounds__(256, 4) void k_gate(
    const float* __restrict__ x, const float* __restrict__ gcw,
    const float* __restrict__ gcb, float* __restrict__ g_mean) {
  __shared__ float xs[3 * 34 * 34];  // 13872 B zero-padded halo
  __shared__ float red[4 * 16];
  const int b = blockIdx.x;
  const int t = threadIdx.x;
  const float* xb = x + (size_t)b * 3072;

  for (int c = t; c < 3468; c += 256) {
    const int ci = c / 1156;
    const int rem = c - ci * 1156;
    const int y = rem / 34;
    const int xx = rem - y * 34;
    const int gy = y - 1, gx = xx - 1;
    float v = 0.f;
    if (gy >= 0 && gy < 32 && gx >= 0 && gx < 32) v = xb[ci * 1024 + gy * 32 + gx];
    xs[c] = v;
  }
  __syncthreads();

  const int r = t >> 3;        // output row 0..31
  const int c0 = (t & 7) * 4;  // output col base

  float accp[16][4];
#pragma unroll
  for (int c = 0; c < 16; c++)
#pragma unroll
    for (int p = 0; p < 4; p++) accp[c][p] = 0.f;

#pragma unroll
  for (int ci = 0; ci < 3; ci++) {
    float pv[3][6];
#pragma unroll
    for (int dy = 0; dy < 3; dy++) {
      const float* row = xs + ci * 1156 + (r + dy) * 34 + c0;
#pragma unroll
      for (int dx = 0; dx < 6; dx++) pv[dy][dx] = row[dx];
    }
#pragma unroll
    for (int c = 0; c < 16; c++) {
      const float* wr = gcw + (c * 3 + ci) * 9;
#pragma unroll
      for (int ky = 0; ky < 3; ky++)
#pragma unroll
        for (int kx = 0; kx < 3; kx++) {
          const float wv = wr[ky * 3 + kx];
#pragma unroll
          for (int p = 0; p < 4; p++)
            accp[c][p] += wv * pv[ky][kx + p];
        }
    }
  }

  float sums[16];
#pragma unroll
  for (int c = 0; c < 16; c++) {
    const float bb = gcb[c];
    float s = 0.f;
#pragma unroll
    for (int p = 0; p < 4; p++) s += fmaxf(accp[c][p] + bb, 0.f);
    sums[c] = s;
  }

  const int wave = t >> 6, lane = t & 63;
#pragma unroll
  for (int c = 0; c < 16; c++) {
    float v = sums[c];
    for (int o = 32; o > 0; o >>= 1) v += __shfl_down(v, o);
    if (lane == 0) red[wave * 16 + c] = v;
  }
  __syncthreads();
  if (t < 16) {
    g_mean[b * 16 + t] =
        (red[t] + red[16 + t] + red[32 + t] + red[48 + t]) * (1.f / 1024.f);
  }
}

// ---------------- K2: router linear+softmax, argmax, counts ----------------
__global__ __launch_bounds__(256) void k_router(
    const float* __restrict__ g_mean, const float* __restrict__ gfw,
    const float* __restrict__ gfb, float* __restrict__ probs,
    float* __restrict__ best_w, int* __restrict__ best_idx,
    int* __restrict__ counts) {
  const int b = blockIdx.x * 256 + threadIdx.x;
  float g[16];
#pragma unroll
  for (int c = 0; c < 16; c++) g[c] = g_mean[b * 16 + c];
  float lg[4];
#pragma unroll
  for (int e = 0; e < 4; e++) {
    float s = gfb[e];
#pragma unroll
    for (int c = 0; c < 16; c++) s += g[c] * gfw[e * 16 + c];
    lg[e] = s;
  }
  float m = fmaxf(fmaxf(lg[0], lg[1]), fmaxf(lg[2], lg[3]));
  float ex[4], s = 0.f;
#pragma unroll
  for (int e = 0; e < 4; e++) { ex[e] = expf(lg[e] - m); s += ex[e]; }
  const float inv = 1.f / s;
  float p[4];
#pragma unroll
  for (int e = 0; e < 4; e++) { p[e] = ex[e] * inv; probs[b * 4 + e] = p[e]; }
  int bi = 0; float bp = p[0];
#pragma unroll
  for (int e = 1; e < 4; e++) if (p[e] > bp) { bp = p[e]; bi = e; }
  best_w[b] = bp;
  best_idx[b] = bi;
  atomicAdd(&counts[bi], 1);
}

// ---------------- K2c: 32-aligned segment offsets --------------------------
__global__ void k_offsets(const int* __restrict__ counts, int* __restrict__ off) {
  if (threadIdx.x == 0) {
    int o = 0;
    for (int e = 0; e < 4; e++) { off[e] = o; o += ((counts[e] + 31) & ~31); }
    off[4] = o;
  }
}

// ---------------- K2d: scatter sample ids grouped by expert ----------------
__global__ __launch_bounds__(256) void k_scatter(
    const int* __restrict__ best_idx, const int* __restrict__ off,
    int* __restrict__ cnt2, int* __restrict__ order) {
  const int b = blockIdx.x * 256 + threadIdx.x;
  const int e = best_idx[b];
  const int slot = off[e] + atomicAdd(&cnt2[e], 1);
  order[slot] = b;
}

// ---------------- K3: aux loss ---------------------------------------------
__global__ __launch_bounds__(256) void k_aux(const float* __restrict__ probs,
                                             float* __restrict__ aux_out) {
  __shared__ float red[16];
  const int t = threadIdx.x;
  const int wave = t >> 6, lane = t & 63;
  float sums[4] = {0.f, 0.f, 0.f, 0.f};
  for (int b = t; b < B_TOT; b += 256) {
#pragma unroll
    for (int e = 0; e < 4; e++) sums[e] += probs[b * 4 + e];
  }
#pragma unroll
  for (int e = 0; e < 4; e++) {
    float v = sums[e];
    for (int o = 32; o > 0; o >>= 1) v += __shfl_down(v, o);
    if (lane == 0) red[wave * 4 + e] = v;
  }
  __syncthreads();
  if (t == 0) {
    float aux = 0.f;
#pragma unroll
    for (int e = 0; e < 4; e++) {
      const float mp = (red[e] + red[4 + e] + red[8 + e] + red[12 + e]) * (1.f / 1024.f);
      const float d = mp - 0.25f;
      aux += d * d;
    }
    aux_out[0] = aux * 0.25f;
  }
}

// ---------------- K4: expert conv1(3->64)+relu+pool -> h1 bf16 [b][pos][ci] -
__global__ __launch_bounds__(256, 2) void k_conv1(
    const float* __restrict__ x, const float* __restrict__ w1,
    const float* __restrict__ b1, const int* __restrict__ best_idx,
    ushort* __restrict__ h1q) {
  const int b = blockIdx.x;
  const int tid = threadIdx.x;
  const int wave = __builtin_amdgcn_readfirstlane(tid >> 6);
  const int lane = tid & 63;
  const int e = __builtin_amdgcn_readfirstlane(best_idx[b]);
  const int pos = wave * 64 + lane;  // pooled position 0..255
  const int py = pos >> 4, px = pos & 15;
  const float* xb = x + (size_t)b * 3072;
  const float* w1e = w1 + (size_t)e * 1728;
  const float* b1e = b1 + (size_t)e * 64;
  ushort* h1b = h1q + (size_t)b * 16384;

  int ry[4], cx[4];
  float my[4], mx_[4];
#pragma unroll
  for (int i = 0; i < 4; i++) {
    const int yy = 2 * py - 1 + i;
    my[i] = (yy >= 0 && yy < 32) ? 1.f : 0.f;
    ry[i] = min(max(yy, 0), 31) * 32;
    const int xx = 2 * px - 1 + i;
    mx_[i] = (xx >= 0 && xx < 32) ? 1.f : 0.f;
    cx[i] = min(max(xx, 0), 31);
  }
  float mm[16];
#pragma unroll
  for (int i = 0; i < 4; i++)
#pragma unroll
    for (int j = 0; j < 4; j++) mm[i * 4 + j] = my[i] * mx_[j];

  for (int g = 0; g < 8; g++) {
    const int co0 = g * 8;
    float acc[8][4];
#pragma unroll
    for (int m = 0; m < 8; m++)
#pragma unroll
      for (int q = 0; q < 4; q++) acc[m][q] = 0.f;
#pragma unroll
    for (int ci = 0; ci < 3; ci++) {
      float pv[16];
#pragma unroll
      for (int i = 0; i < 4; i++)
#pragma unroll
        for (int j = 0; j < 4; j++)
          pv[i * 4 + j] = xb[ci * 1024 + ry[i] + cx[j]] * mm[i * 4 + j];
#pragma unroll
      for (int m = 0; m < 8; m++) {
        const float* wr = w1e + (co0 + m) * 27 + ci * 9;
#pragma unroll
        for (int ky = 0; ky < 3; ky++)
#pragma unroll
          for (int kx = 0; kx < 3; kx++) {
            const float wv = wr[ky * 3 + kx];
#pragma unroll
            for (int dy = 0; dy < 2; dy++)
#pragma unroll
              for (int dx = 0; dx < 2; dx++)
                acc[m][dy * 2 + dx] += wv * pv[(ky + dy) * 4 + (kx + dx)];
          }
      }
    }
    union { ushort us[8]; uint4 u4; } pk;
#pragma unroll
    for (int m = 0; m < 8; m++) {
      float v = fmaxf(fmaxf(acc[m][0], acc[m][1]), fmaxf(acc[m][2], acc[m][3]));
      v = fmaxf(v + b1e[co0 + m], 0.f);
      pk.us[m] = f2bf(v);
    }
    *(uint4*)(h1b + pos * 64 + co0) = pk.u4;  // 16B packed, ci-contiguous
  }
}

// ---------------- K4b: conv2 via bf16 MFMA implicit GEMM -> h2 bf16 --------
__global__ __launch_bounds__(256) void k_conv2(
    const ushort* __restrict__ h1q, const ushort* __restrict__ wp,
    const float* __restrict__ b2, const int* __restrict__ best_idx,
    ushort* __restrict__ h2q) {
  __shared__ uint4 st[864];   // [row 6][cig 8][col 18] x 16B (8 ci bf16)
  __shared__ float pl[2048];  // [coutL 128][pooled 16]
  const int blk = blockIdx.x;
  const int b = blk >> 2;
  const int yq = blk & 3;  // out rows yq*4 .. yq*4+3
  const int t = threadIdx.x;
  const int e = __builtin_amdgcn_readfirstlane(best_idx[b]);

  // stage h1 rows yq*4-1 .. yq*4+4 (zero-padded) into LDS
  for (int c = t; c < 864; c += 256) {
    const int row = c / 144;           // 8*18
    const int rem = c - row * 144;
    const int cig = rem / 18;
    const int col = rem - cig * 18;
    const int gy = yq * 4 - 1 + row;
    uint4 v = make_uint4(0u, 0u, 0u, 0u);
    if (gy >= 0 && gy < 16 && col >= 1 && col <= 16)
      v = *(const uint4*)(h1q + ((size_t)b * 256 + gy * 16 + col - 1) * 64 + cig * 8);
    st[c] = v;  // c == (row*8+cig)*18+col
  }
  __syncthreads();

  const int wv = t >> 6;
  const int lane = t & 63;
  const int n = lane & 31;        // spatial within n-tile
  const int half = lane >> 5;     // k-half: ci offset half*8
  const int drow = n >> 4;
  const int col = n & 15;
  const int cout0 = wv * 32;

  f32x16 acc0, acc1;
#pragma unroll
  for (int i = 0; i < 16; i++) { acc0[i] = 0.f; acc1[i] = 0.f; }

  const ushort* wpa = wp + (size_t)e * 73728 + (size_t)(cout0 + n) * 64 + half * 8;
  const short* sb = (const short*)st;

  for (int kk = 0; kk < 9; kk++) {
    const int ky = kk / 3;
    const int kx = kk - ky * 3;
#pragma unroll
    for (int c4 = 0; c4 < 4; c4++) {
      const int ci0 = c4 * 16;
      const int cig = c4 * 2 + half;
      const short8 af = *(const short8*)(wpa + kk * 8192 + ci0);
      const short8 bf0 = *(const short8*)(sb + (((drow + ky) * 8 + cig) * 18 + col + kx) * 8);
      const short8 bf1 = *(const short8*)(sb + (((2 + drow + ky) * 8 + cig) * 18 + col + kx) * 8);
      acc0 = __builtin_amdgcn_mfma_f32_32x32x16_bf16(af, bf0, acc0, 0, 0, 0);
      acc1 = __builtin_amdgcn_mfma_f32_32x32x16_bf16(af, bf1, acc1, 0, 0, 0);
    }
  }

  // fused 2x2 maxpool: cols via shfl_xor(1), rows via shfl_xor(16)
#pragma unroll
  for (int tt = 0; tt < 2; tt++) {
    const f32x16 a = tt ? acc1 : acc0;
#pragma unroll
    for (int r = 0; r < 16; r++) {
      float v = a[r];
      v = fmaxf(v, __shfl_xor(v, 1));
      v = fmaxf(v, __shfl_xor(v, 16));
      if ((lane & 17) == 0) {  // n even, drow==0
        const int rowm = (r & 3) + 8 * (r >> 2) + 4 * half;
        const int pc = n >> 1;  // 0..7
        pl[(cout0 + rowm) * 16 + tt * 8 + pc] = v;
      }
    }
  }
  __syncthreads();

  // bias + relu + bf16 pack + coalesced write: h2[b][cout][yq*16 + p]
  {
    const int coutL = t >> 1;
    const int hh = t & 1;
    const float bias = b2[e * 128 + coutL];
    const float* src = pl + coutL * 16 + hh * 8;
    union { ushort us[8]; uint4 u4; } pk;
#pragma unroll
    for (int j = 0; j < 8; j++) pk.us[j] = f2bf(fmaxf(src[j] + bias, 0.f));
    *(uint4*)(h2q + (size_t)b * 8192 + coutL * 64 + yq * 16 + hh * 8) = pk.u4;
  }
}

// ---------------- K5: FC via bf16 MFMA, expert-grouped, split-K=16 ---------
// Grid (36, 16). Block 256 = 4 waves; wave w: cout 32w..32w+31 x 32 samples.
// K-slice 512 = 2 chunks of 256 staged in LDS [kb 32][sample 32][8].
__global__ __launch_bounds__(256) void k_fc(
    const ushort* __restrict__ h2q, const ushort* __restrict__ wfc,
    const float* __restrict__ efb, const int* __restrict__ order,
    const int* __restrict__ off, const int* __restrict__ counts,
    const float* __restrict__ best_w, float* __restrict__ out) {
  __shared__ ushort bs[32 * 32 * 8];  // 16 KB
  __shared__ int sid[32];
  __shared__ float sbw[32];
  const int tix = blockIdx.x;
  const int ks = blockIdx.y;  // K-slice of 512
  const int base = tix * 32;
  if (base >= off[4]) return;
  int e = 0;
#pragma unroll
  for (int i = 1; i < 4; i++) if (base >= off[i]) e = i;
  const int vend = off[e] + counts[e];
  const int t = threadIdx.x;
  if (t < 32) {
    const int pos = base + t;
    const bool v = pos < vend;
    const int s = v ? order[pos] : -1;
    sid[t] = s;
    sbw[t] = v ? best_w[s] : 0.f;
  }
  __syncthreads();

  const int lane = t & 63;
  const int wv = t >> 6;
  const int half = lane >> 5;
  const int mn = lane & 31;
  const int cout0 = wv * 32;
  const int ss = t & 31;        // staging sample
  const int kgrp = t >> 5;      // staging kb sub-index 0..7
  const int srow = sid[ss] >= 0 ? sid[ss] : 0;  // safe row (tile has >=1 valid)
  const ushort* arow = h2q + (size_t)srow * 8192;

  f32x16 acc;
#pragma unroll
  for (int i = 0; i < 16; i++) acc[i] = 0.f;

  const ushort* wbase = wfc + ((size_t)e * 1024 + (size_t)ks * 64) * 1024;  // [kb][128][8]
  const short* sb = (const short*)bs;

#pragma unroll
  for (int ch = 0; ch < 2; ch++) {
    const int k0g = ks * 512 + ch * 256;
    if (ch) __syncthreads();
#pragma unroll
    for (int p = 0; p < 4; p++) {
      const int kb = p * 8 + kgrp;
      const uint4 v = *(const uint4*)(arow + k0g + kb * 8);
      *(uint4*)(bs + (kb * 32 + ss) * 8) = v;
    }
    __syncthreads();
#pragma unroll
    for (int kk = 0; kk < 16; kk++) {
      const int kbl = kk * 2 + half;          // kb within chunk
      const short8 af = *(const short8*)(wbase +
          ((size_t)(ch * 32 + kbl) * 128 + cout0 + mn) * 8);
      const short8 bf = *(const short8*)(sb + (kbl * 32 + mn) * 8);
      acc = __builtin_amdgcn_mfma_f32_32x32x16_bf16(af, bf, acc, 0, 0, 0);
    }
  }

  // epilogue: C[cout][sample], col=lane&31=sample, row=(r&3)+8*(r>>2)+4*half
  const int so = sid[mn];
  if (so >= 0) {
    const float bw = sbw[mn];
#pragma unroll
    for (int r = 0; r < 16; r++) {
      const int cout = cout0 + (r & 3) + 8 * (r >> 2) + 4 * half;
      if (cout < 100) {
        float v = acc[r] * bw;
        if (ks == 0) v += efb[e * 100 + cout] * bw;
        atomicAdd(out + (size_t)so * 100 + cout, v);
      }
    }
  }
}

// ---------------------------------------------------------------------------
extern "C" void kernel_launch(void* const* d_in, const int* in_sizes, int n_in,
                              void* d_out, int out_size, void* d_ws, size_t ws_size,
                              hipStream_t stream) {
  const float* x   = (const float*)d_in[0];
  const float* gcw = (const float*)d_in[1];
  const float* gcb = (const float*)d_in[2];
  const float* gfw = (const float*)d_in[3];
  const float* gfb = (const float*)d_in[4];
  const float* c1w = (const float*)d_in[5];
  const float* c1b = (const float*)d_in[6];
  const float* c2w = (const float*)d_in[7];
  const float* c2b = (const float*)d_in[8];
  const float* efw = (const float*)d_in[9];
  const float* efb = (const float*)d_in[10];
  float* out = (float*)d_out;
  float* ws  = (float*)d_ws;

  // ws layout (float-element offsets)
  float*  g_mean   = ws;                        // 16384
  float*  best_w   = ws + 16384;                // 1024
  int*    best_idx = (int*)(ws + 17408);        // 1024
  int*    counts   = (int*)(ws + 18432);        // 4
  int*    cnt2     = (int*)(ws + 18436);        // 4
  int*    off      = (int*)(ws + 18440);        // 5
  int*    order    = (int*)(ws + 18448);        // 1152
  ushort* wp       = (ushort*)(ws + 20480);     // 294912 us  = 147456 f
  ushort* wfc      = (ushort*)(ws + 167936);    // 4194304 us = 2097152 f
  ushort* h1       = (ushort*)(ws + 2265088);   // 16777216 us = 8388608 f
  ushort* h2q      = (ushort*)(ws + 10653696);  // 8388608 us = 4194304 f

  float* probs = out + 102400;
  float* aux   = out + 106496;

  hipMemsetAsync(out, 0, 102400 * sizeof(float), stream);  // atomic target
  hipMemsetAsync(counts, 0, 8 * sizeof(int), stream);      // counts + cnt2

  k_wprep<<<1152, 256, 0, stream>>>(c2w, wp);
  k_wfc<<<16384, 256, 0, stream>>>(efw, wfc);
  k_gate<<<1024, 256, 0, stream>>>(x, gcw, gcb, g_mean);
  k_router<<<4, 256, 0, stream>>>(g_mean, gfw, gfb, probs, best_w, best_idx, counts);
  k_offsets<<<1, 64, 0, stream>>>(counts, off);
  k_scatter<<<4, 256, 0, stream>>>(best_idx, off, cnt2, order);
  k_aux<<<1, 256, 0, stream>>>(probs, aux);
  k_conv1<<<1024, 256, 0, stream>>>(x, c1w, c1b, best_idx, h1);
  k_conv2<<<4096, 256, 0, stream>>>(h1, wp, c2b, best_idx, h2q);
  dim3 g5(36, 16);
  k_fc<<<g5, 256, 0, stream>>>(h2q, wfc, efb, order, off, counts, best_w, out);
}

// Round 6
// 349.305 us; speedup vs baseline: 7.4515x; 1.1050x over previous
//
#include <hip/hip_runtime.h>
#include <hip/hip_bf16.h>
#include <cstdint>

// ---------------------------------------------------------------------------
// MoE CNN, hard top-1 dispatch. Round 6: k_conv1 -> LDS halo + reg patch +
// coalesced bf16 writes (h1 layout [b][cig][pos][8]).
// Sizes: B=1024, Cin=3, HW=32, GC=16, E=4, C1=64, C2=128, FC_IN=8192, NC=100
// Output: [final 1024*100][probs 1024*4][aux 1]
// ---------------------------------------------------------------------------

#define B_TOT 1024

typedef __attribute__((ext_vector_type(8))) short short8;
typedef __attribute__((ext_vector_type(16))) float f32x16;

__device__ __forceinline__ ushort f2bf(float f) {
  uint32_t u = __float_as_uint(f);
  u += 0x7fffu + ((u >> 16) & 1u);  // round-to-nearest-even
  return (ushort)(u >> 16);
}

// ---------------- K0: w2 fp32 [e][cout][ci][3][3] -> bf16 [e][kk][cout][ci] -
__global__ __launch_bounds__(256) void k_wprep(const float* __restrict__ w2,
                                               ushort* __restrict__ wp) {
  const int i = blockIdx.x * 256 + threadIdx.x;  // 294912 total
  const int ci = i & 63;
  const int cout = (i >> 6) & 127;
  const int kkE = i >> 13;          // e*9 + kk, 0..35
  const int kk = kkE - (kkE / 9) * 9;
  const int e = kkE / 9;
  const float f = w2[(size_t)(((e * 128 + cout) * 64 + ci) * 9) + kk];
  wp[i] = f2bf(f);
}

// ---------------- K0b: efw fp32 [e][100][8192] -> bf16 [e][kb][cout128][8] -
__global__ __launch_bounds__(256) void k_wfc(const float* __restrict__ efw,
                                             ushort* __restrict__ wfc) {
  const int i = blockIdx.x * 256 + threadIdx.x;  // 4194304 total
  const int j = i & 7;
  const int cout = (i >> 3) & 127;
  const int kb = (i >> 10) & 1023;
  const int e = i >> 20;
  const int k = kb * 8 + j;
  float f = 0.f;
  if (cout < 100) f = efw[((size_t)(e * 100 + cout)) * 8192 + k];
  wfc[i] = f2bf(f);
}

// ---------------- K1: gate conv(3->16)+relu+gap, LDS halo, maskless --------
__global__ __launch_bounds__(256, 4) void k_gate(
    const float* __restrict__ x, const float* __restrict__ gcw,
    const float* __restrict__ gcb, float* __restrict__ g_mean) {
  __shared__ float xs[3 * 34 * 34];  // 13872 B zero-padded halo
  __shared__ float red[4 * 16];
  const int b = blockIdx.x;
  const int t = threadIdx.x;
  const float* xb = x + (size_t)b * 3072;

  for (int c = t; c < 3468; c += 256) {
    const int ci = c / 1156;
    const int rem = c - ci * 1156;
    const int y = rem / 34;
    const int xx = rem - y * 34;
    const int gy = y - 1, gx = xx - 1;
    float v = 0.f;
    if (gy >= 0 && gy < 32 && gx >= 0 && gx < 32) v = xb[ci * 1024 + gy * 32 + gx];
    xs[c] = v;
  }
  __syncthreads();

  const int r = t >> 3;        // output row 0..31
  const int c0 = (t & 7) * 4;  // output col base

  float accp[16][4];
#pragma unroll
  for (int c = 0; c < 16; c++)
#pragma unroll
    for (int p = 0; p < 4; p++) accp[c][p] = 0.f;

#pragma unroll
  for (int ci = 0; ci < 3; ci++) {
    float pv[3][6];
#pragma unroll
    for (int dy = 0; dy < 3; dy++) {
      const float* row = xs + ci * 1156 + (r + dy) * 34 + c0;
#pragma unroll
      for (int dx = 0; dx < 6; dx++) pv[dy][dx] = row[dx];
    }
#pragma unroll
    for (int c = 0; c < 16; c++) {
      const float* wr = gcw + (c * 3 + ci) * 9;
#pragma unroll
      for (int ky = 0; ky < 3; ky++)
#pragma unroll
        for (int kx = 0; kx < 3; kx++) {
          const float wv = wr[ky * 3 + kx];
#pragma unroll
          for (int p = 0; p < 4; p++)
            accp[c][p] += wv * pv[ky][kx + p];
        }
    }
  }

  float sums[16];
#pragma unroll
  for (int c = 0; c < 16; c++) {
    const float bb = gcb[c];
    float s = 0.f;
#pragma unroll
    for (int p = 0; p < 4; p++) s += fmaxf(accp[c][p] + bb, 0.f);
    sums[c] = s;
  }

  const int wave = t >> 6, lane = t & 63;
#pragma unroll
  for (int c = 0; c < 16; c++) {
    float v = sums[c];
    for (int o = 32; o > 0; o >>= 1) v += __shfl_down(v, o);
    if (lane == 0) red[wave * 16 + c] = v;
  }
  __syncthreads();
  if (t < 16) {
    g_mean[b * 16 + t] =
        (red[t] + red[16 + t] + red[32 + t] + red[48 + t]) * (1.f / 1024.f);
  }
}

// ---------------- K2: router linear+softmax, argmax, counts ----------------
__global__ __launch_bounds__(256) void k_router(
    const float* __restrict__ g_mean, const float* __restrict__ gfw,
    const float* __restrict__ gfb, float* __restrict__ probs,
    float* __restrict__ best_w, int* __restrict__ best_idx,
    int* __restrict__ counts) {
  const int b = blockIdx.x * 256 + threadIdx.x;
  float g[16];
#pragma unroll
  for (int c = 0; c < 16; c++) g[c] = g_mean[b * 16 + c];
  float lg[4];
#pragma unroll
  for (int e = 0; e < 4; e++) {
    float s = gfb[e];
#pragma unroll
    for (int c = 0; c < 16; c++) s += g[c] * gfw[e * 16 + c];
    lg[e] = s;
  }
  float m = fmaxf(fmaxf(lg[0], lg[1]), fmaxf(lg[2], lg[3]));
  float ex[4], s = 0.f;
#pragma unroll
  for (int e = 0; e < 4; e++) { ex[e] = expf(lg[e] - m); s += ex[e]; }
  const float inv = 1.f / s;
  float p[4];
#pragma unroll
  for (int e = 0; e < 4; e++) { p[e] = ex[e] * inv; probs[b * 4 + e] = p[e]; }
  int bi = 0; float bp = p[0];
#pragma unroll
  for (int e = 1; e < 4; e++) if (p[e] > bp) { bp = p[e]; bi = e; }
  best_w[b] = bp;
  best_idx[b] = bi;
  atomicAdd(&counts[bi], 1);
}

// ---------------- K2c: 32-aligned segment offsets --------------------------
__global__ void k_offsets(const int* __restrict__ counts, int* __restrict__ off) {
  if (threadIdx.x == 0) {
    int o = 0;
    for (int e = 0; e < 4; e++) { off[e] = o; o += ((counts[e] + 31) & ~31); }
    off[4] = o;
  }
}

// ---------------- K2d: scatter sample ids grouped by expert ----------------
__global__ __launch_bounds__(256) void k_scatter(
    const int* __restrict__ best_idx, const int* __restrict__ off,
    int* __restrict__ cnt2, int* __restrict__ order) {
  const int b = blockIdx.x * 256 + threadIdx.x;
  const int e = best_idx[b];
  const int slot = off[e] + atomicAdd(&cnt2[e], 1);
  order[slot] = b;
}

// ---------------- K3: aux loss ---------------------------------------------
__global__ __launch_bounds__(256) void k_aux(const float* __restrict__ probs,
                                             float* __restrict__ aux_out) {
  __shared__ float red[16];
  const int t = threadIdx.x;
  const int wave = t >> 6, lane = t & 63;
  float sums[4] = {0.f, 0.f, 0.f, 0.f};
  for (int b = t; b < B_TOT; b += 256) {
#pragma unroll
    for (int e = 0; e < 4; e++) sums[e] += probs[b * 4 + e];
  }
#pragma unroll
  for (int e = 0; e < 4; e++) {
    float v = sums[e];
    for (int o = 32; o > 0; o >>= 1) v += __shfl_down(v, o);
    if (lane == 0) red[wave * 4 + e] = v;
  }
  __syncthreads();
  if (t == 0) {
    float aux = 0.f;
#pragma unroll
    for (int e = 0; e < 4; e++) {
      const float mp = (red[e] + red[4 + e] + red[8 + e] + red[12 + e]) * (1.f / 1024.f);
      const float d = mp - 0.25f;
      aux += d * d;
    }
    aux_out[0] = aux * 0.25f;
  }
}

// ---------------- K4: conv1(3->64)+relu+pool, LDS halo, reg patch ----------
// Block per sample. Thread = pooled pos. h1 layout: [b][cig 8][pos 256][8]
// -> wave stores are lane-contiguous (fully coalesced uint4).
__global__ __launch_bounds__(256, 4) void k_conv1(
    const float* __restrict__ x, const float* __restrict__ w1,
    const float* __restrict__ b1, const int* __restrict__ best_idx,
    ushort* __restrict__ h1q) {
  __shared__ float xs[3 * 34 * 34];  // zero-padded halo
  const int b = blockIdx.x;
  const int t = threadIdx.x;
  const int e = __builtin_amdgcn_readfirstlane(best_idx[b]);
  const float* xb = x + (size_t)b * 3072;
  const float* w1e = w1 + (size_t)e * 1728;
  const float* b1e = b1 + (size_t)e * 64;

  for (int c = t; c < 3468; c += 256) {
    const int ci = c / 1156;
    const int rem = c - ci * 1156;
    const int y = rem / 34;
    const int xx = rem - y * 34;
    const int gy = y - 1, gx = xx - 1;
    float v = 0.f;
    if (gy >= 0 && gy < 32 && gx >= 0 && gx < 32) v = xb[ci * 1024 + gy * 32 + gx];
    xs[c] = v;
  }
  __syncthreads();

  const int py = t >> 4, px = t & 15;
  // 4x4 pre-pool patch (halo coords): rows 2py..2py+3, cols 2px..2px+3
  float pv[3][4][4];
#pragma unroll
  for (int ci = 0; ci < 3; ci++)
#pragma unroll
    for (int i = 0; i < 4; i++) {
      const float* row = xs + ci * 1156 + (2 * py + i) * 34 + 2 * px;
#pragma unroll
      for (int j = 0; j < 4; j++) pv[ci][i][j] = row[j];
    }

  ushort* h1b = h1q + (size_t)b * 16384 + t * 8;  // + cig*2048
#pragma unroll
  for (int g = 0; g < 8; g++) {
    float acc[8][4];
#pragma unroll
    for (int m = 0; m < 8; m++)
#pragma unroll
      for (int q = 0; q < 4; q++) acc[m][q] = 0.f;
#pragma unroll
    for (int m = 0; m < 8; m++) {
      const float* wr = w1e + (g * 8 + m) * 27;
#pragma unroll
      for (int ci = 0; ci < 3; ci++)
#pragma unroll
        for (int ky = 0; ky < 3; ky++)
#pragma unroll
          for (int kx = 0; kx < 3; kx++) {
            const float wv = wr[ci * 9 + ky * 3 + kx];
#pragma unroll
            for (int dy = 0; dy < 2; dy++)
#pragma unroll
              for (int dx = 0; dx < 2; dx++)
                acc[m][dy * 2 + dx] += wv * pv[ci][ky + dy][kx + dx];
          }
    }
    union { ushort us[8]; uint4 u4; } pk;
#pragma unroll
    for (int m = 0; m < 8; m++) {
      float v = fmaxf(fmaxf(acc[m][0], acc[m][1]), fmaxf(acc[m][2], acc[m][3]));
      pk.us[m] = f2bf(fmaxf(v + b1e[g * 8 + m], 0.f));
    }
    *(uint4*)(h1b + g * 2048) = pk.u4;  // lane-contiguous across the wave
  }
}

// ---------------- K4b: conv2 via bf16 MFMA implicit GEMM -> h2 bf16 --------
__global__ __launch_bounds__(256) void k_conv2(
    const ushort* __restrict__ h1q, const ushort* __restrict__ wp,
    const float* __restrict__ b2, const int* __restrict__ best_idx,
    ushort* __restrict__ h2q) {
  __shared__ uint4 st[864];   // [row 6][cig 8][col 18] x 16B (8 ci bf16)
  __shared__ float pl[2048];  // [coutL 128][pooled 16]
  const int blk = blockIdx.x;
  const int b = blk >> 2;
  const int yq = blk & 3;  // out rows yq*4 .. yq*4+3
  const int t = threadIdx.x;
  const int e = __builtin_amdgcn_readfirstlane(best_idx[b]);

  // stage h1 rows yq*4-1 .. yq*4+4 (zero-padded) into LDS
  // h1 layout: [b][cig 8][pos 256][8]
  for (int c = t; c < 864; c += 256) {
    const int row = c / 144;           // 8*18
    const int rem = c - row * 144;
    const int cig = rem / 18;
    const int col = rem - cig * 18;
    const int gy = yq * 4 - 1 + row;
    uint4 v = make_uint4(0u, 0u, 0u, 0u);
    if (gy >= 0 && gy < 16 && col >= 1 && col <= 16)
      v = *(const uint4*)(h1q + (size_t)b * 16384 + cig * 2048 +
                          (gy * 16 + col - 1) * 8);
    st[c] = v;  // c == (row*8+cig)*18+col
  }
  __syncthreads();

  const int wv = t >> 6;
  const int lane = t & 63;
  const int n = lane & 31;        // spatial within n-tile
  const int half = lane >> 5;     // k-half: ci offset half*8
  const int drow = n >> 4;
  const int col = n & 15;
  const int cout0 = wv * 32;

  f32x16 acc0, acc1;
#pragma unroll
  for (int i = 0; i < 16; i++) { acc0[i] = 0.f; acc1[i] = 0.f; }

  const ushort* wpa = wp + (size_t)e * 73728 + (size_t)(cout0 + n) * 64 + half * 8;
  const short* sb = (const short*)st;

  for (int kk = 0; kk < 9; kk++) {
    const int ky = kk / 3;
    const int kx = kk - ky * 3;
#pragma unroll
    for (int c4 = 0; c4 < 4; c4++) {
      const int ci0 = c4 * 16;
      const int cig = c4 * 2 + half;
      const short8 af = *(const short8*)(wpa + kk * 8192 + ci0);
      const short8 bf0 = *(const short8*)(sb + (((drow + ky) * 8 + cig) * 18 + col + kx) * 8);
      const short8 bf1 = *(const short8*)(sb + (((2 + drow + ky) * 8 + cig) * 18 + col + kx) * 8);
      acc0 = __builtin_amdgcn_mfma_f32_32x32x16_bf16(af, bf0, acc0, 0, 0, 0);
      acc1 = __builtin_amdgcn_mfma_f32_32x32x16_bf16(af, bf1, acc1, 0, 0, 0);
    }
  }

  // fused 2x2 maxpool: cols via shfl_xor(1), rows via shfl_xor(16)
#pragma unroll
  for (int tt = 0; tt < 2; tt++) {
    const f32x16 a = tt ? acc1 : acc0;
#pragma unroll
    for (int r = 0; r < 16; r++) {
      float v = a[r];
      v = fmaxf(v, __shfl_xor(v, 1));
      v = fmaxf(v, __shfl_xor(v, 16));
      if ((lane & 17) == 0) {  // n even, drow==0
        const int rowm = (r & 3) + 8 * (r >> 2) + 4 * half;
        const int pc = n >> 1;  // 0..7
        pl[(cout0 + rowm) * 16 + tt * 8 + pc] = v;
      }
    }
  }
  __syncthreads();

  // bias + relu + bf16 pack + coalesced write: h2[b][cout][yq*16 + p]
  {
    const int coutL = t >> 1;
    const int hh = t & 1;
    const float bias = b2[e * 128 + coutL];
    const float* src = pl + coutL * 16 + hh * 8;
    union { ushort us[8]; uint4 u4; } pk;
#pragma unroll
    for (int j = 0; j < 8; j++) pk.us[j] = f2bf(fmaxf(src[j] + bias, 0.f));
    *(uint4*)(h2q + (size_t)b * 8192 + coutL * 64 + yq * 16 + hh * 8) = pk.u4;
  }
}

// ---------------- K5: FC via bf16 MFMA, expert-grouped, split-K=16 ---------
__global__ __launch_bounds__(256) void k_fc(
    const ushort* __restrict__ h2q, const ushort* __restrict__ wfc,
    const float* __restrict__ efb, const int* __restrict__ order,
    const int* __restrict__ off, const int* __restrict__ counts,
    const float* __restrict__ best_w, float* __restrict__ out) {
  __shared__ ushort bs[32 * 32 * 8];  // 16 KB
  __shared__ int sid[32];
  __shared__ float sbw[32];
  const int tix = blockIdx.x;
  const int ks = blockIdx.y;  // K-slice of 512
  const int base = tix * 32;
  if (base >= off[4]) return;
  int e = 0;
#pragma unroll
  for (int i = 1; i < 4; i++) if (base >= off[i]) e = i;
  const int vend = off[e] + counts[e];
  const int t = threadIdx.x;
  if (t < 32) {
    const int pos = base + t;
    const bool v = pos < vend;
    const int s = v ? order[pos] : -1;
    sid[t] = s;
    sbw[t] = v ? best_w[s] : 0.f;
  }
  __syncthreads();

  const int lane = t & 63;
  const int wv = t >> 6;
  const int half = lane >> 5;
  const int mn = lane & 31;
  const int cout0 = wv * 32;
  const int ss = t & 31;        // staging sample
  const int kgrp = t >> 5;      // staging kb sub-index 0..7
  const int srow = sid[ss] >= 0 ? sid[ss] : 0;  // safe row
  const ushort* arow = h2q + (size_t)srow * 8192;

  f32x16 acc;
#pragma unroll
  for (int i = 0; i < 16; i++) acc[i] = 0.f;

  const ushort* wbase = wfc + ((size_t)e * 1024 + (size_t)ks * 64) * 1024;  // [kb][128][8]
  const short* sb = (const short*)bs;

#pragma unroll
  for (int ch = 0; ch < 2; ch++) {
    const int k0g = ks * 512 + ch * 256;
    if (ch) __syncthreads();
#pragma unroll
    for (int p = 0; p < 4; p++) {
      const int kb = p * 8 + kgrp;
      const uint4 v = *(const uint4*)(arow + k0g + kb * 8);
      *(uint4*)(bs + (kb * 32 + ss) * 8) = v;
    }
    __syncthreads();
#pragma unroll
    for (int kk = 0; kk < 16; kk++) {
      const int kbl = kk * 2 + half;          // kb within chunk
      const short8 af = *(const short8*)(wbase +
          ((size_t)(ch * 32 + kbl) * 128 + cout0 + mn) * 8);
      const short8 bf = *(const short8*)(sb + (kbl * 32 + mn) * 8);
      acc = __builtin_amdgcn_mfma_f32_32x32x16_bf16(af, bf, acc, 0, 0, 0);
    }
  }

  // epilogue: C[cout][sample], col=lane&31=sample, row=(r&3)+8*(r>>2)+4*half
  const int so = sid[mn];
  if (so >= 0) {
    const float bw = sbw[mn];
#pragma unroll
    for (int r = 0; r < 16; r++) {
      const int cout = cout0 + (r & 3) + 8 * (r >> 2) + 4 * half;
      if (cout < 100) {
        float v = acc[r] * bw;
        if (ks == 0) v += efb[e * 100 + cout] * bw;
        atomicAdd(out + (size_t)so * 100 + cout, v);
      }
    }
  }
}

// ---------------------------------------------------------------------------
extern "C" void kernel_launch(void* const* d_in, const int* in_sizes, int n_in,
                              void* d_out, int out_size, void* d_ws, size_t ws_size,
                              hipStream_t stream) {
  const float* x   = (const float*)d_in[0];
  const float* gcw = (const float*)d_in[1];
  const float* gcb = (const float*)d_in[2];
  const float* gfw = (const float*)d_in[3];
  const float* gfb = (const float*)d_in[4];
  const float* c1w = (const float*)d_in[5];
  const float* c1b = (const float*)d_in[6];
  const float* c2w = (const float*)d_in[7];
  const float* c2b = (const float*)d_in[8];
  const float* efw = (const float*)d_in[9];
  const float* efb = (const float*)d_in[10];
  float* out = (float*)d_out;
  float* ws  = (float*)d_ws;

  // ws layout (float-element offsets)
  float*  g_mean   = ws;                        // 16384
  float*  best_w   = ws + 16384;                // 1024
  int*    best_idx = (int*)(ws + 17408);        // 1024
  int*    counts   = (int*)(ws + 18432);        // 4
  int*    cnt2     = (int*)(ws + 18436);        // 4
  int*    off      = (int*)(ws + 18440);        // 5
  int*    order    = (int*)(ws + 18448);        // 1152
  ushort* wp       = (ushort*)(ws + 20480);     // 294912 us  = 147456 f
  ushort* wfc      = (ushort*)(ws + 167936);    // 4194304 us = 2097152 f
  ushort* h1       = (ushort*)(ws + 2265088);   // 16777216 us = 8388608 f
  ushort* h2q      = (ushort*)(ws + 10653696);  // 8388608 us = 4194304 f

  float* probs = out + 102400;
  float* aux   = out + 106496;

  hipMemsetAsync(out, 0, 102400 * sizeof(float), stream);  // atomic target
  hipMemsetAsync(counts, 0, 8 * sizeof(int), stream);      // counts + cnt2

  k_wprep<<<1152, 256, 0, stream>>>(c2w, wp);
  k_wfc<<<16384, 256, 0, stream>>>(efw, wfc);
  k_gate<<<1024, 256, 0, stream>>>(x, gcw, gcb, g_mean);
  k_router<<<4, 256, 0, stream>>>(g_mean, gfw, gfb, probs, best_w, best_idx, counts);
  k_offsets<<<1, 64, 0, stream>>>(counts, off);
  k_scatter<<<4, 256, 0, stream>>>(best_idx, off, cnt2, order);
  k_aux<<<1, 256, 0, stream>>>(probs, aux);
  k_conv1<<<1024, 256, 0, stream>>>(x, c1w, c1b, best_idx, h1);
  k_conv2<<<4096, 256, 0, stream>>>(h1, wp, c2b, best_idx, h2q);
  dim3 g5(36, 16);
  k_fc<<<g5, 256, 0, stream>>>(h2q, wfc, efb, order, off, counts, best_w, out);
}